// Round 2
// baseline (796.653 us; speedup 1.0000x reference)
//
#include <hip/hip_runtime.h>
#include <cstdint>
#include <cstddef>

// ---------------- problem constants ----------------
#define HH 208
#define WW 336
#define NA 3
#define NPER 209664      // H*W*A per image
#define NROWS 139776     // B*H*W
#define NB 2
#define PRE_K 2000
#define POST_K 1000
#define CAP 8192         // candidate capacity per image (power of 2 for bitonic)
#define MW 32            // 64-bit words per mask row (32*64 = 2048 >= 2000)
#define MROWS 2048
#define BBOX_CLIP_F 4.135166556742356f

// ---------------- ws layout (bytes) ----------------
// [0)      hist       : NB*4096*4   = 32768
// [32768)  hist2      : NB*4096*4   = 32768   (ends 65536)
// [65536)  meta_T     : NB*4
// [65544)  meta_T24   : NB*4
// [65552)  cand_count : NB*4
// [65560)  keep_count : NB*4
// [65568)  cand       : NB*CAP*8    = 131072  (ends 196640)
// [196640) sboxes     : NB*2000*4*4 = 64000   (ends 260640)
// [260640) sscores    : NB*2000*4   = 16000   (ends 276640)
// [276640) keep       : NB*1000*4   = 8000    (ends 284640)
// [284640) mask       : NB*2048*32*8= 1048576 (ends 1333216)
#define WS_HIST  0
#define WS_HIST2 32768
#define WS_META  65536
#define WS_META24 65544
#define WS_CCNT  65552
#define WS_KCNT  65560
#define WS_CAND  65568
#define WS_SBOX  196640
#define WS_SSC   260640
#define WS_KEEP  276640
#define WS_MASK  284640
#define WS_ZERO_WORDS 49160   // zero [0, 196640) as u32

// ---------------- helpers ----------------
__device__ __forceinline__ float sigmoidf_ref(float x) {
  return __fdiv_rn(1.0f, __fadd_rn(1.0f, expf(-x)));
}
__device__ __forceinline__ unsigned int score_u(float logit) {
  float s = sigmoidf_ref(logit);            // s in (0,1), sign bit 0
  return __float_as_uint(s) | 0x80000000u;  // orderable
}

// decode box for anchor n of image b; matches reference op-by-op (no FMA contraction)
__device__ __forceinline__ float4 decode_box(const float* __restrict__ bbox,
                                             int b, unsigned int n,
                                             float hmax, float wmax) {
  unsigned int a = n % 3u;
  unsigned int pix = n / 3u;
  unsigned int y = pix / (unsigned int)WW;
  unsigned int x = pix % (unsigned int)WW;
  float yc = ((float)y + 0.5f) * 4.0f;   // exact in f32
  float xc = ((float)x + 0.5f) * 4.0f;   // exact in f32
  float hx = (a == 0) ? 16.0f : ((a == 1) ? 22.4f : 11.2f);
  float hy = (a == 0) ? 16.0f : ((a == 1) ? 11.2f : 22.4f);
  float ay1 = __fsub_rn(yc, hy), ax1 = __fsub_rn(xc, hx);
  float ay2 = __fadd_rn(yc, hy), ax2 = __fadd_rn(xc, hx);
  float ah = __fsub_rn(ay2, ay1), aw = __fsub_rn(ax2, ax1);
  float acy = __fadd_rn(ay1, __fmul_rn(0.5f, ah));
  float acx = __fadd_rn(ax1, __fmul_rn(0.5f, aw));
  const float* d = bbox + ((size_t)b * NPER + n) * 4u;
  float dy = d[0], dx = d[1];
  float dh = fminf(fmaxf(d[2], -BBOX_CLIP_F), BBOX_CLIP_F);
  float dw = fminf(fmaxf(d[3], -BBOX_CLIP_F), BBOX_CLIP_F);
  float cy = __fadd_rn(__fmul_rn(dy, ah), acy);
  float cx = __fadd_rn(__fmul_rn(dx, aw), acx);
  float hh = __fmul_rn(expf(dh), ah);
  float wwv = __fmul_rn(expf(dw), aw);
  float y1 = __fsub_rn(cy, __fmul_rn(0.5f, hh));
  float x1 = __fsub_rn(cx, __fmul_rn(0.5f, wwv));
  float y2 = __fadd_rn(cy, __fmul_rn(0.5f, hh));
  float x2 = __fadd_rn(cx, __fmul_rn(0.5f, wwv));
  y1 = fminf(fmaxf(y1, 0.0f), hmax);
  x1 = fminf(fmaxf(x1, 0.0f), wmax);
  y2 = fminf(fmaxf(y2, 0.0f), hmax);
  x2 = fminf(fmaxf(x2, 0.0f), wmax);
  return make_float4(y1, x1, y2, x2);
}

// reference IoU, exact op order
__device__ __forceinline__ float iou_ref(float4 bi, float4 bj) {
  float yA = fmaxf(bi.x, bj.x);
  float xA = fmaxf(bi.y, bj.y);
  float yB = fminf(bi.z, bj.z);
  float xB = fminf(bi.w, bj.w);
  float inter = __fmul_rn(fmaxf(__fsub_rn(yB, yA), 0.0f),
                          fmaxf(__fsub_rn(xB, xA), 0.0f));
  float a1 = __fmul_rn(__fsub_rn(bi.z, bi.x), __fsub_rn(bi.w, bi.y));
  float a2 = __fmul_rn(__fsub_rn(bj.z, bj.x), __fsub_rn(bj.w, bj.y));
  float den = __fadd_rn(__fsub_rn(__fadd_rn(a1, a2), inter), 1e-8f);
  return __fdiv_rn(inter, den);
}

// ---------------- K0: zero ws prefix ----------------
__global__ void k_zero(unsigned int* __restrict__ p, int n) {
  int i = blockIdx.x * blockDim.x + threadIdx.x;
  if (i < n) p[i] = 0u;
}

// ---------------- K1: head GEMM (wave-per-row) ----------------
__global__ __launch_bounds__(256) void k_head(
    const float* __restrict__ feats, const float* __restrict__ w_cls,
    const float* __restrict__ b_cls, const float* __restrict__ w_reg,
    const float* __restrict__ b_reg, float* __restrict__ out_cls,
    float* __restrict__ out_bbox) {
  const int lane = threadIdx.x & 63;
  const int wid = blockIdx.x * (blockDim.x >> 6) + (threadIdx.x >> 6);
  const int nw = gridDim.x * (blockDim.x >> 6);
  const int k0 = lane << 2;
  float wc[4][3], wr[4][12];
#pragma unroll
  for (int kk = 0; kk < 4; ++kk) {
#pragma unroll
    for (int o = 0; o < 3; ++o) wc[kk][o] = w_cls[(k0 + kk) * 3 + o];
#pragma unroll
    for (int o = 0; o < 12; ++o) wr[kk][o] = w_reg[(k0 + kk) * 12 + o];
  }
  float bc[3], br[12];
#pragma unroll
  for (int o = 0; o < 3; ++o) bc[o] = b_cls[o];
#pragma unroll
  for (int o = 0; o < 12; ++o) br[o] = b_reg[o];

  for (int r = wid; r < NROWS; r += nw) {
    const float4 f4 = *(const float4*)(feats + (size_t)r * 256 + k0);
    const float fv[4] = {f4.x, f4.y, f4.z, f4.w};
    float acc[15];
#pragma unroll
    for (int o = 0; o < 15; ++o) acc[o] = 0.0f;
#pragma unroll
    for (int kk = 0; kk < 4; ++kk) {
#pragma unroll
      for (int o = 0; o < 3; ++o) acc[o] += fv[kk] * wc[kk][o];
#pragma unroll
      for (int o = 0; o < 12; ++o) acc[3 + o] += fv[kk] * wr[kk][o];
    }
#pragma unroll
    for (int off = 32; off >= 1; off >>= 1) {
#pragma unroll
      for (int o = 0; o < 15; ++o) acc[o] += __shfl_xor(acc[o], off, 64);
    }
    if (lane == 0) {
#pragma unroll
      for (int o = 0; o < 3; ++o) out_cls[(size_t)r * 3 + o] = acc[o] + bc[o];
#pragma unroll
      for (int o = 0; o < 12; ++o) out_bbox[(size_t)r * 12 + o] = acc[3 + o] + br[o];
    }
  }
}

// ---------------- K2: 12-bit prefix histogram (LDS-staged) ----------------
__global__ __launch_bounds__(256) void k_hist(const float* __restrict__ out_cls,
                                              unsigned int* __restrict__ hist) {
  const int b = blockIdx.y;
  __shared__ unsigned int h[4096];
  for (int i = threadIdx.x; i < 4096; i += blockDim.x) h[i] = 0u;
  __syncthreads();
  for (int i = blockIdx.x * blockDim.x + threadIdx.x; i < NPER;
       i += gridDim.x * blockDim.x) {
    unsigned int u = score_u(out_cls[(size_t)b * NPER + i]);
    atomicAdd(&h[u >> 20], 1u);
  }
  __syncthreads();
  for (int i = threadIdx.x; i < 4096; i += blockDim.x)
    if (h[i]) atomicAdd(&hist[b * 4096 + i], h[i]);
}

// ---------------- K3: coarse threshold bin scan (1 block / image) ----------------
__global__ __launch_bounds__(1024) void k_thresh(const unsigned int* __restrict__ hist,
                                                 unsigned int* __restrict__ meta_T) {
  const int b = blockIdx.x;
  const int t = threadIdx.x;
  __shared__ unsigned int sums[1024];
  unsigned int hb[4];
  unsigned int s = 0u;
#pragma unroll
  for (int q = 0; q < 4; ++q) {
    int bin = 4095 - (t * 4 + q);   // descending bins
    hb[q] = hist[b * 4096 + bin];
    s += hb[q];
  }
  sums[t] = s;
  __syncthreads();
  for (int off = 1; off < 1024; off <<= 1) {
    unsigned int v = (t >= off) ? sums[t - off] : 0u;
    __syncthreads();
    sums[t] += v;
    __syncthreads();
  }
  unsigned int excl = sums[t] - s;  // count in bins above my chunk
  if (excl < PRE_K && excl + s >= PRE_K) {
    unsigned int c = excl;
#pragma unroll
    for (int q = 0; q < 4; ++q) {
      c += hb[q];
      if (c >= PRE_K) { meta_T[b] = (unsigned int)(4095 - (t * 4 + q)); break; }
    }
  }
}

// ---------------- K3b: refine histogram (next 12 bits, items in bin T only) ----------------
__global__ __launch_bounds__(256) void k_hist2(const float* __restrict__ out_cls,
                                               const unsigned int* __restrict__ meta_T,
                                               unsigned int* __restrict__ hist2) {
  const int b = blockIdx.y;
  const unsigned int T = meta_T[b];
  __shared__ unsigned int h[4096];
  for (int i = threadIdx.x; i < 4096; i += blockDim.x) h[i] = 0u;
  __syncthreads();
  for (int i = blockIdx.x * blockDim.x + threadIdx.x; i < NPER;
       i += gridDim.x * blockDim.x) {
    unsigned int u = score_u(out_cls[(size_t)b * NPER + i]);
    if ((u >> 20) == T) atomicAdd(&h[(u >> 8) & 0xFFFu], 1u);
  }
  __syncthreads();
  for (int i = threadIdx.x; i < 4096; i += blockDim.x)
    if (h[i]) atomicAdd(&hist2[b * 4096 + i], h[i]);
}

// ---------------- K3c: refined 24-bit threshold (1 block / image) ----------------
__global__ __launch_bounds__(1024) void k_thresh2(const unsigned int* __restrict__ hist,
                                                  const unsigned int* __restrict__ hist2,
                                                  const unsigned int* __restrict__ meta_T,
                                                  unsigned int* __restrict__ meta_T24) {
  const int b = blockIdx.x;
  const int t = threadIdx.x;
  const unsigned int T = meta_T[b];
  __shared__ unsigned int sums[1024];
  __shared__ unsigned int c0s;
  // C0 = number of items in coarse bins strictly above T  (C0 < PRE_K by construction)
  unsigned int c0 = 0u;
  for (int i = t; i < 4096; i += 1024)
    if ((unsigned int)i > T) c0 += hist[b * 4096 + i];
  sums[t] = c0;
  __syncthreads();
  for (int off = 512; off > 0; off >>= 1) {
    if (t < off) sums[t] += sums[t + off];
    __syncthreads();
  }
  if (t == 0) c0s = sums[0];
  __syncthreads();
  const unsigned int C0 = c0s;
  __syncthreads();
  // descending prefix over hist2
  unsigned int hb[4];
  unsigned int s = 0u;
#pragma unroll
  for (int q = 0; q < 4; ++q) {
    int bin = 4095 - (t * 4 + q);
    hb[q] = hist2[b * 4096 + bin];
    s += hb[q];
  }
  sums[t] = s;
  __syncthreads();
  for (int off = 1; off < 1024; off <<= 1) {
    unsigned int v = (t >= off) ? sums[t - off] : 0u;
    __syncthreads();
    sums[t] += v;
    __syncthreads();
  }
  unsigned int excl = sums[t] - s;
  if (C0 + excl < PRE_K && C0 + excl + s >= PRE_K) {
    unsigned int c = C0 + excl;
#pragma unroll
    for (int q = 0; q < 4; ++q) {
      c += hb[q];
      if (c >= PRE_K) {
        meta_T24[b] = (T << 12) | (unsigned int)(4095 - (t * 4 + q));
        break;
      }
    }
  }
}

// ---------------- K4: compact candidates (24-bit threshold) ----------------
__global__ __launch_bounds__(256) void k_compact(const float* __restrict__ out_cls,
                                                 const unsigned int* __restrict__ meta_T24,
                                                 unsigned int* __restrict__ cand_count,
                                                 unsigned long long* __restrict__ cand) {
  const int b = blockIdx.y;
  const unsigned int T24 = meta_T24[b];
  for (int i = blockIdx.x * blockDim.x + threadIdx.x; i < NPER;
       i += gridDim.x * blockDim.x) {
    unsigned int u = score_u(out_cls[(size_t)b * NPER + i]);
    if ((u >> 8) >= T24) {
      unsigned int pos = atomicAdd(&cand_count[b], 1u);
      if (pos < CAP)
        cand[(size_t)b * CAP + pos] =
            ((unsigned long long)u << 32) | (unsigned int)(~(unsigned int)i);
    }
  }
}

// ---------------- K5: bitonic sort (desc) + gather/decode top-2000 ----------------
__global__ __launch_bounds__(1024) void k_sort(const unsigned long long* __restrict__ cand,
                                               const float* __restrict__ out_bbox,
                                               const float* __restrict__ img_info,
                                               float* __restrict__ sboxes,
                                               float* __restrict__ sscores) {
  const int b = blockIdx.x;
  const int t = threadIdx.x;
  __shared__ unsigned long long keys[CAP];   // 64 KiB
  for (int i = t; i < CAP; i += 1024) keys[i] = cand[(size_t)b * CAP + i];
  __syncthreads();
  for (int k = 2; k <= CAP; k <<= 1) {
    for (int j = k >> 1; j > 0; j >>= 1) {
      for (int i = t; i < CAP; i += 1024) {
        int ixj = i ^ j;
        if (ixj > i) {
          unsigned long long a = keys[i], c = keys[ixj];
          bool up = ((i & k) == 0);
          bool sw = up ? (a < c) : (a > c);   // descending overall
          if (sw) { keys[i] = c; keys[ixj] = a; }
        }
      }
      __syncthreads();
    }
  }
  const float hmax = img_info[b * 2 + 0];
  const float wmax = img_info[b * 2 + 1];
  for (int i = t; i < PRE_K; i += 1024) {
    unsigned long long key = keys[i];
    unsigned int u = (unsigned int)(key >> 32);
    unsigned int idx = ~(unsigned int)(key & 0xFFFFFFFFull);
    float sc = __uint_as_float(u & 0x7FFFFFFFu);
    float4 bx = decode_box(out_bbox, b, idx, hmax, wmax);
    ((float4*)sboxes)[(size_t)b * PRE_K + i] = bx;
    sscores[(size_t)b * PRE_K + i] = sc;
  }
}

// ---------------- K6: pairwise suppression mask ----------------
__global__ __launch_bounds__(64) void k_mask(const float* __restrict__ sboxes,
                                             unsigned long long* __restrict__ mask) {
  const int b = blockIdx.z;
  const int rb = blockIdx.x;
  const int cb = blockIdx.y;
  const int t = threadIdx.x;
  __shared__ float4 cbox[64];
  const int col0 = cb * 64;
  {
    int c = col0 + t;
    cbox[t] = (c < PRE_K) ? ((const float4*)sboxes)[(size_t)b * PRE_K + c]
                          : make_float4(0.f, 0.f, 0.f, 0.f);
  }
  __syncthreads();
  const int i = rb * 64 + t;
  if (i >= PRE_K) return;
  float4 bi = ((const float4*)sboxes)[(size_t)b * PRE_K + i];
  unsigned long long bits = 0ull;
#pragma unroll 8
  for (int j = 0; j < 64; ++j) {
    int c = col0 + j;
    if (c > i && c < PRE_K) {
      if (iou_ref(bi, cbox[j]) > 0.7f) bits |= (1ull << j);
    }
  }
  mask[((size_t)b * MROWS + i) * MW + cb] = bits;
}

// ---------------- K7: single-wave sequential keep scan ----------------
__global__ __launch_bounds__(64) void k_scan(const unsigned long long* __restrict__ mask,
                                             unsigned int* __restrict__ keep,
                                             unsigned int* __restrict__ keep_count) {
  const int b = blockIdx.x;
  const int lane = threadIdx.x;
  const unsigned long long* M = mask + (size_t)b * MROWS * MW;
  unsigned long long remv = 0ull;
  int nk = 0;
  unsigned long long m0 = (lane < MW) ? M[0 * MW + lane] : 0ull;
  unsigned long long m1 = (lane < MW) ? M[1 * MW + lane] : 0ull;
  for (int i = 0; i < PRE_K; ++i) {
    unsigned long long mnext =
        ((i + 2) < PRE_K && lane < MW) ? M[(size_t)(i + 2) * MW + lane] : 0ull;
    unsigned long long w = __shfl(remv, i >> 6, 64);
    bool alive = (((w >> (i & 63)) & 1ull) == 0ull);
    if (alive) {
      if (lane == 0) keep[b * POST_K + nk] = (unsigned int)i;
      ++nk;
      remv |= m0;
      if (nk >= POST_K) break;
    }
    m0 = m1;
    m1 = mnext;
  }
  if (lane == 0) keep_count[b] = (unsigned int)nk;
}

// ---------------- K8: write rois / roi_scores (with padding) ----------------
__global__ __launch_bounds__(256) void k_write(const float* __restrict__ sboxes,
                                               const float* __restrict__ sscores,
                                               const unsigned int* __restrict__ keep,
                                               const unsigned int* __restrict__ keep_count,
                                               float* __restrict__ rois,
                                               float* __restrict__ rsc) {
  const int b = blockIdx.y;
  const int i = blockIdx.x * blockDim.x + threadIdx.x;
  if (i >= POST_K) return;
  const unsigned int K = keep_count[b];
  float4 bx;
  float s;
  if ((unsigned int)i < K) {
    unsigned int j = keep[b * POST_K + i];
    bx = ((const float4*)sboxes)[(size_t)b * PRE_K + j];
    s = sscores[(size_t)b * PRE_K + j];
  } else {
    bx = ((const float4*)sboxes)[(size_t)b * PRE_K + 0];  // boxes[argmax of all -1] = boxes[0]
    s = -1.0f;
  }
  ((float4*)rois)[(size_t)b * POST_K + i] = bx;
  rsc[(size_t)b * POST_K + i] = s;
}

// ---------------- launch ----------------
extern "C" void kernel_launch(void* const* d_in, const int* in_sizes, int n_in,
                              void* d_out, int out_size, void* d_ws, size_t ws_size,
                              hipStream_t stream) {
  const float* feats    = (const float*)d_in[0];
  const float* img_info = (const float*)d_in[1];
  const float* w_cls    = (const float*)d_in[2];
  const float* b_cls    = (const float*)d_in[3];
  const float* w_reg    = (const float*)d_in[4];
  const float* b_reg    = (const float*)d_in[5];

  float* out = (float*)d_out;
  float* out_cls  = out;              // [2,208,336,3]  = 419328
  float* out_bbox = out + 419328;     // [2,208,336,12] = 1677312
  float* out_rois = out + 2096640;    // [2,1000,4]     = 8000
  float* out_rsc  = out + 2104640;    // [2,1000]       = 2000

  char* ws = (char*)d_ws;
  unsigned int* hist        = (unsigned int*)(ws + WS_HIST);
  unsigned int* hist2       = (unsigned int*)(ws + WS_HIST2);
  unsigned int* meta_T      = (unsigned int*)(ws + WS_META);
  unsigned int* meta_T24    = (unsigned int*)(ws + WS_META24);
  unsigned int* cand_count  = (unsigned int*)(ws + WS_CCNT);
  unsigned int* keep_count  = (unsigned int*)(ws + WS_KCNT);
  unsigned long long* cand  = (unsigned long long*)(ws + WS_CAND);
  float* sboxes             = (float*)(ws + WS_SBOX);
  float* sscores            = (float*)(ws + WS_SSC);
  unsigned int* keep        = (unsigned int*)(ws + WS_KEEP);
  unsigned long long* mask  = (unsigned long long*)(ws + WS_MASK);

  k_zero<<<(WS_ZERO_WORDS + 255) / 256, 256, 0, stream>>>((unsigned int*)ws, WS_ZERO_WORDS);
  k_head<<<2048, 256, 0, stream>>>(feats, w_cls, b_cls, w_reg, b_reg, out_cls, out_bbox);
  k_hist<<<dim3(128, NB), 256, 0, stream>>>(out_cls, hist);
  k_thresh<<<NB, 1024, 0, stream>>>(hist, meta_T);
  k_hist2<<<dim3(128, NB), 256, 0, stream>>>(out_cls, meta_T, hist2);
  k_thresh2<<<NB, 1024, 0, stream>>>(hist, hist2, meta_T, meta_T24);
  k_compact<<<dim3(128, NB), 256, 0, stream>>>(out_cls, meta_T24, cand_count, cand);
  k_sort<<<NB, 1024, 0, stream>>>(cand, out_bbox, img_info, sboxes, sscores);
  k_mask<<<dim3(32, 32, NB), 64, 0, stream>>>(sboxes, mask);
  k_scan<<<NB, 64, 0, stream>>>(mask, keep, keep_count);
  k_write<<<dim3(4, NB), 256, 0, stream>>>(sboxes, sscores, keep, keep_count, out_rois, out_rsc);
}

// Round 3
// 551.676 us; speedup vs baseline: 1.4441x; 1.4441x over previous
//
#include <hip/hip_runtime.h>
#include <cstdint>
#include <cstddef>

// ---------------- problem constants ----------------
#define HH 208
#define WW 336
#define NA 3
#define NPER 209664      // H*W*A per image
#define NROWS 139776     // B*H*W
#define NB 2
#define PRE_K 2000
#define POST_K 1000
#define CAP 8192         // candidate capacity per image (power of 2 for bitonic)
#define MW 32            // 64-bit words per mask row (32*64 = 2048 >= 2000)
#define MROWS 2048
#define BBOX_CLIP_F 4.135166556742356f

// ---------------- ws layout (bytes) ----------------
#define WS_HIST  0
#define WS_HIST2 32768
#define WS_META  65536
#define WS_META24 65544
#define WS_CCNT  65552
#define WS_KCNT  65560
#define WS_CAND  65568
#define WS_SBOX  196640
#define WS_SSC   260640
#define WS_KEEP  276640
#define WS_MASK  284640
#define WS_ZERO_WORDS 49160   // zero [0, 196640) as u32 (hist, hist2, meta, counts, cand)

// ---------------- helpers ----------------
__device__ __forceinline__ float sigmoidf_ref(float x) {
  return __fdiv_rn(1.0f, __fadd_rn(1.0f, expf(-x)));
}
__device__ __forceinline__ unsigned int score_u(float logit) {
  float s = sigmoidf_ref(logit);            // s in (0,1), sign bit 0
  return __float_as_uint(s) | 0x80000000u;  // orderable
}

// decode box for anchor n of image b; matches reference op-by-op (no FMA contraction)
__device__ __forceinline__ float4 decode_box(const float* __restrict__ bbox,
                                             int b, unsigned int n,
                                             float hmax, float wmax) {
  unsigned int a = n % 3u;
  unsigned int pix = n / 3u;
  unsigned int y = pix / (unsigned int)WW;
  unsigned int x = pix % (unsigned int)WW;
  float yc = ((float)y + 0.5f) * 4.0f;   // exact in f32
  float xc = ((float)x + 0.5f) * 4.0f;   // exact in f32
  float hx = (a == 0) ? 16.0f : ((a == 1) ? 22.4f : 11.2f);
  float hy = (a == 0) ? 16.0f : ((a == 1) ? 11.2f : 22.4f);
  float ay1 = __fsub_rn(yc, hy), ax1 = __fsub_rn(xc, hx);
  float ay2 = __fadd_rn(yc, hy), ax2 = __fadd_rn(xc, hx);
  float ah = __fsub_rn(ay2, ay1), aw = __fsub_rn(ax2, ax1);
  float acy = __fadd_rn(ay1, __fmul_rn(0.5f, ah));
  float acx = __fadd_rn(ax1, __fmul_rn(0.5f, aw));
  const float* d = bbox + ((size_t)b * NPER + n) * 4u;
  float dy = d[0], dx = d[1];
  float dh = fminf(fmaxf(d[2], -BBOX_CLIP_F), BBOX_CLIP_F);
  float dw = fminf(fmaxf(d[3], -BBOX_CLIP_F), BBOX_CLIP_F);
  float cy = __fadd_rn(__fmul_rn(dy, ah), acy);
  float cx = __fadd_rn(__fmul_rn(dx, aw), acx);
  float hh = __fmul_rn(expf(dh), ah);
  float wwv = __fmul_rn(expf(dw), aw);
  float y1 = __fsub_rn(cy, __fmul_rn(0.5f, hh));
  float x1 = __fsub_rn(cx, __fmul_rn(0.5f, wwv));
  float y2 = __fadd_rn(cy, __fmul_rn(0.5f, hh));
  float x2 = __fadd_rn(cx, __fmul_rn(0.5f, wwv));
  y1 = fminf(fmaxf(y1, 0.0f), hmax);
  x1 = fminf(fmaxf(x1, 0.0f), wmax);
  y2 = fminf(fmaxf(y2, 0.0f), hmax);
  x2 = fminf(fmaxf(x2, 0.0f), wmax);
  return make_float4(y1, x1, y2, x2);
}

// reference IoU, exact op order
__device__ __forceinline__ float iou_ref(float4 bi, float4 bj) {
  float yA = fmaxf(bi.x, bj.x);
  float xA = fmaxf(bi.y, bj.y);
  float yB = fminf(bi.z, bj.z);
  float xB = fminf(bi.w, bj.w);
  float inter = __fmul_rn(fmaxf(__fsub_rn(yB, yA), 0.0f),
                          fmaxf(__fsub_rn(xB, xA), 0.0f));
  float a1 = __fmul_rn(__fsub_rn(bi.z, bi.x), __fsub_rn(bi.w, bi.y));
  float a2 = __fmul_rn(__fsub_rn(bj.z, bj.x), __fsub_rn(bj.w, bj.y));
  float den = __fadd_rn(__fsub_rn(__fadd_rn(a1, a2), inter), 1e-8f);
  return __fdiv_rn(inter, den);
}

// ---------------- K0: zero ws prefix ----------------
__global__ void k_zero(unsigned int* __restrict__ p, int n) {
  int i = blockIdx.x * blockDim.x + threadIdx.x;
  if (i < n) p[i] = 0u;
}

// ---------------- K1: head GEMM (wave-per-row) ----------------
__global__ __launch_bounds__(256) void k_head(
    const float* __restrict__ feats, const float* __restrict__ w_cls,
    const float* __restrict__ b_cls, const float* __restrict__ w_reg,
    const float* __restrict__ b_reg, float* __restrict__ out_cls,
    float* __restrict__ out_bbox) {
  const int lane = threadIdx.x & 63;
  const int wid = blockIdx.x * (blockDim.x >> 6) + (threadIdx.x >> 6);
  const int nw = gridDim.x * (blockDim.x >> 6);
  const int k0 = lane << 2;
  float wc[4][3], wr[4][12];
#pragma unroll
  for (int kk = 0; kk < 4; ++kk) {
#pragma unroll
    for (int o = 0; o < 3; ++o) wc[kk][o] = w_cls[(k0 + kk) * 3 + o];
#pragma unroll
    for (int o = 0; o < 12; ++o) wr[kk][o] = w_reg[(k0 + kk) * 12 + o];
  }
  float bc[3], br[12];
#pragma unroll
  for (int o = 0; o < 3; ++o) bc[o] = b_cls[o];
#pragma unroll
  for (int o = 0; o < 12; ++o) br[o] = b_reg[o];

  for (int r = wid; r < NROWS; r += nw) {
    const float4 f4 = *(const float4*)(feats + (size_t)r * 256 + k0);
    const float fv[4] = {f4.x, f4.y, f4.z, f4.w};
    float acc[15];
#pragma unroll
    for (int o = 0; o < 15; ++o) acc[o] = 0.0f;
#pragma unroll
    for (int kk = 0; kk < 4; ++kk) {
#pragma unroll
      for (int o = 0; o < 3; ++o) acc[o] += fv[kk] * wc[kk][o];
#pragma unroll
      for (int o = 0; o < 12; ++o) acc[3 + o] += fv[kk] * wr[kk][o];
    }
#pragma unroll
    for (int off = 32; off >= 1; off >>= 1) {
#pragma unroll
      for (int o = 0; o < 15; ++o) acc[o] += __shfl_xor(acc[o], off, 64);
    }
    if (lane == 0) {
#pragma unroll
      for (int o = 0; o < 3; ++o) out_cls[(size_t)r * 3 + o] = acc[o] + bc[o];
#pragma unroll
      for (int o = 0; o < 12; ++o) out_bbox[(size_t)r * 12 + o] = acc[3 + o] + br[o];
    }
  }
}

// ---------------- K2: 12-bit prefix histogram (LDS-staged) ----------------
__global__ __launch_bounds__(256) void k_hist(const float* __restrict__ out_cls,
                                              unsigned int* __restrict__ hist) {
  const int b = blockIdx.y;
  __shared__ unsigned int h[4096];
  for (int i = threadIdx.x; i < 4096; i += blockDim.x) h[i] = 0u;
  __syncthreads();
  for (int i = blockIdx.x * blockDim.x + threadIdx.x; i < NPER;
       i += gridDim.x * blockDim.x) {
    unsigned int u = score_u(out_cls[(size_t)b * NPER + i]);
    atomicAdd(&h[u >> 20], 1u);
  }
  __syncthreads();
  for (int i = threadIdx.x; i < 4096; i += blockDim.x)
    if (h[i]) atomicAdd(&hist[b * 4096 + i], h[i]);
}

// ---------------- K3: coarse threshold bin scan (1 block / image) ----------------
__global__ __launch_bounds__(1024) void k_thresh(const unsigned int* __restrict__ hist,
                                                 unsigned int* __restrict__ meta_T) {
  const int b = blockIdx.x;
  const int t = threadIdx.x;
  __shared__ unsigned int sums[1024];
  unsigned int hb[4];
  unsigned int s = 0u;
#pragma unroll
  for (int q = 0; q < 4; ++q) {
    int bin = 4095 - (t * 4 + q);   // descending bins
    hb[q] = hist[b * 4096 + bin];
    s += hb[q];
  }
  sums[t] = s;
  __syncthreads();
  for (int off = 1; off < 1024; off <<= 1) {
    unsigned int v = (t >= off) ? sums[t - off] : 0u;
    __syncthreads();
    sums[t] += v;
    __syncthreads();
  }
  unsigned int excl = sums[t] - s;  // count in bins above my chunk
  if (excl < PRE_K && excl + s >= PRE_K) {
    unsigned int c = excl;
#pragma unroll
    for (int q = 0; q < 4; ++q) {
      c += hb[q];
      if (c >= PRE_K) { meta_T[b] = (unsigned int)(4095 - (t * 4 + q)); break; }
    }
  }
}

// ---------------- K3b: refine histogram (next 12 bits, items in bin T only) ----------------
__global__ __launch_bounds__(256) void k_hist2(const float* __restrict__ out_cls,
                                               const unsigned int* __restrict__ meta_T,
                                               unsigned int* __restrict__ hist2) {
  const int b = blockIdx.y;
  const unsigned int T = meta_T[b];
  __shared__ unsigned int h[4096];
  for (int i = threadIdx.x; i < 4096; i += blockDim.x) h[i] = 0u;
  __syncthreads();
  for (int i = blockIdx.x * blockDim.x + threadIdx.x; i < NPER;
       i += gridDim.x * blockDim.x) {
    unsigned int u = score_u(out_cls[(size_t)b * NPER + i]);
    if ((u >> 20) == T) atomicAdd(&h[(u >> 8) & 0xFFFu], 1u);
  }
  __syncthreads();
  for (int i = threadIdx.x; i < 4096; i += blockDim.x)
    if (h[i]) atomicAdd(&hist2[b * 4096 + i], h[i]);
}

// ---------------- K3c: refined 24-bit threshold (1 block / image) ----------------
__global__ __launch_bounds__(1024) void k_thresh2(const unsigned int* __restrict__ hist,
                                                  const unsigned int* __restrict__ hist2,
                                                  const unsigned int* __restrict__ meta_T,
                                                  unsigned int* __restrict__ meta_T24) {
  const int b = blockIdx.x;
  const int t = threadIdx.x;
  const unsigned int T = meta_T[b];
  __shared__ unsigned int sums[1024];
  __shared__ unsigned int c0s;
  unsigned int c0 = 0u;
  for (int i = t; i < 4096; i += 1024)
    if ((unsigned int)i > T) c0 += hist[b * 4096 + i];
  sums[t] = c0;
  __syncthreads();
  for (int off = 512; off > 0; off >>= 1) {
    if (t < off) sums[t] += sums[t + off];
    __syncthreads();
  }
  if (t == 0) c0s = sums[0];
  __syncthreads();
  const unsigned int C0 = c0s;
  __syncthreads();
  unsigned int hb[4];
  unsigned int s = 0u;
#pragma unroll
  for (int q = 0; q < 4; ++q) {
    int bin = 4095 - (t * 4 + q);
    hb[q] = hist2[b * 4096 + bin];
    s += hb[q];
  }
  sums[t] = s;
  __syncthreads();
  for (int off = 1; off < 1024; off <<= 1) {
    unsigned int v = (t >= off) ? sums[t - off] : 0u;
    __syncthreads();
    sums[t] += v;
    __syncthreads();
  }
  unsigned int excl = sums[t] - s;
  if (C0 + excl < PRE_K && C0 + excl + s >= PRE_K) {
    unsigned int c = C0 + excl;
#pragma unroll
    for (int q = 0; q < 4; ++q) {
      c += hb[q];
      if (c >= PRE_K) {
        meta_T24[b] = (T << 12) | (unsigned int)(4095 - (t * 4 + q));
        break;
      }
    }
  }
}

// ---------------- K4: compact candidates (24-bit threshold) ----------------
__global__ __launch_bounds__(256) void k_compact(const float* __restrict__ out_cls,
                                                 const unsigned int* __restrict__ meta_T24,
                                                 unsigned int* __restrict__ cand_count,
                                                 unsigned long long* __restrict__ cand) {
  const int b = blockIdx.y;
  const unsigned int T24 = meta_T24[b];
  for (int i = blockIdx.x * blockDim.x + threadIdx.x; i < NPER;
       i += gridDim.x * blockDim.x) {
    unsigned int u = score_u(out_cls[(size_t)b * NPER + i]);
    if ((u >> 8) >= T24) {
      unsigned int pos = atomicAdd(&cand_count[b], 1u);
      if (pos < CAP)
        cand[(size_t)b * CAP + pos] =
            ((unsigned long long)u << 32) | (unsigned int)(~(unsigned int)i);
    }
  }
}

// ---------------- K5: adaptive bitonic sort (desc) + gather/decode top-2000 ----------------
__global__ __launch_bounds__(1024) void k_sort(const unsigned long long* __restrict__ cand,
                                               const unsigned int* __restrict__ cand_count,
                                               const float* __restrict__ out_bbox,
                                               const float* __restrict__ img_info,
                                               float* __restrict__ sboxes,
                                               float* __restrict__ sscores) {
  const int b = blockIdx.x;
  const int t = threadIdx.x;
  __shared__ unsigned long long keys[CAP];   // 64 KiB
  // sort size: smallest power of two >= cand_count (>= 2048). Buffer beyond
  // cand_count is zero (k_zero), zeros sink to the end in descending order.
  unsigned int cc = cand_count[b];
  if (cc > CAP) cc = CAP;
  int n = 2048;
  while ((unsigned int)n < cc) n <<= 1;
  for (int i = t; i < n; i += 1024) keys[i] = cand[(size_t)b * CAP + i];
  __syncthreads();
  for (int k = 2; k <= n; k <<= 1) {
    for (int j = k >> 1; j > 0; j >>= 1) {
      for (int i = t; i < n; i += 1024) {
        int ixj = i ^ j;
        if (ixj > i) {
          unsigned long long a = keys[i], c = keys[ixj];
          bool up = ((i & k) == 0);
          bool sw = up ? (a < c) : (a > c);   // descending overall
          if (sw) { keys[i] = c; keys[ixj] = a; }
        }
      }
      __syncthreads();
    }
  }
  const float hmax = img_info[b * 2 + 0];
  const float wmax = img_info[b * 2 + 1];
  for (int i = t; i < PRE_K; i += 1024) {
    unsigned long long key = keys[i];
    unsigned int u = (unsigned int)(key >> 32);
    unsigned int idx = ~(unsigned int)(key & 0xFFFFFFFFull);
    float sc = __uint_as_float(u & 0x7FFFFFFFu);
    float4 bx = decode_box(out_bbox, b, idx, hmax, wmax);
    ((float4*)sboxes)[(size_t)b * PRE_K + i] = bx;
    sscores[(size_t)b * PRE_K + i] = sc;
  }
}

// ---------------- K6: pairwise suppression mask ----------------
__global__ __launch_bounds__(64) void k_mask(const float* __restrict__ sboxes,
                                             unsigned long long* __restrict__ mask) {
  const int b = blockIdx.z;
  const int rb = blockIdx.x;
  const int cb = blockIdx.y;
  const int t = threadIdx.x;
  __shared__ float4 cbox[64];
  const int col0 = cb * 64;
  {
    int c = col0 + t;
    cbox[t] = (c < PRE_K) ? ((const float4*)sboxes)[(size_t)b * PRE_K + c]
                          : make_float4(0.f, 0.f, 0.f, 0.f);
  }
  __syncthreads();
  const int i = rb * 64 + t;
  if (i >= PRE_K) return;
  float4 bi = ((const float4*)sboxes)[(size_t)b * PRE_K + i];
  unsigned long long bits = 0ull;
#pragma unroll 8
  for (int j = 0; j < 64; ++j) {
    int c = col0 + j;
    if (c > i && c < PRE_K) {
      if (iou_ref(bi, cbox[j]) > 0.7f) bits |= (1ull << j);
    }
  }
  mask[((size_t)b * MROWS + i) * MW + cb] = bits;
}

// ---------------- K7: single-wave keep scan, deep software pipeline ----------------
// Mask row addresses are independent of the serial suppression state, so keep
// 16-24 loads in flight (3 rotating 8-row register buffers). Chain per row is
// shfl + bit-test + or (~40 cy); load latency ~600 cy / depth ~16 => ~40 cy/row.
#define SCH 8
#define LOAD8(buf, row0)                                            \
  {                                                                 \
    _Pragma("unroll") for (int _j = 0; _j < SCH; ++_j) {            \
      int _r = (row0) + _j;                                         \
      (buf)[_j] = (ldok && _r < PRE_K) ? M[(size_t)_r * MW + lane]  \
                                       : 0ull;                      \
    }                                                               \
  }
#define PROC8(buf, row0)                                            \
  {                                                                 \
    _Pragma("unroll") for (int _j = 0; _j < SCH; ++_j) {            \
      int _i = (row0) + _j;                                         \
      if (_i < PRE_K && nk < POST_K) {                              \
        unsigned long long _w = __shfl(remv, _i >> 6, 64);          \
        if (!((_w >> (_i & 63)) & 1ull)) {                          \
          if (lane == 0) keep[b * POST_K + nk] = (unsigned int)_i;  \
          ++nk;                                                     \
          remv |= (buf)[_j];                                        \
        }                                                           \
      }                                                             \
    }                                                               \
  }

__global__ __launch_bounds__(64) void k_scan(const unsigned long long* __restrict__ mask,
                                             unsigned int* __restrict__ keep,
                                             unsigned int* __restrict__ keep_count) {
  const int b = blockIdx.x;
  const int lane = threadIdx.x;
  const bool ldok = lane < MW;
  const unsigned long long* M = mask + (size_t)b * MROWS * MW;
  unsigned long long remv = 0ull;
  int nk = 0;
  unsigned long long A[SCH], Bf[SCH], Cf[SCH];
  LOAD8(A, 0);
  LOAD8(Bf, SCH);
  LOAD8(Cf, 2 * SCH);
  for (int base = 0; base < PRE_K; base += 3 * SCH) {
    PROC8(A, base);
    LOAD8(A, base + 3 * SCH);
    PROC8(Bf, base + SCH);
    LOAD8(Bf, base + 4 * SCH);
    PROC8(Cf, base + 2 * SCH);
    LOAD8(Cf, base + 5 * SCH);
    if (nk >= POST_K) break;
  }
  if (lane == 0) keep_count[b] = (unsigned int)nk;
}

// ---------------- K8: write rois / roi_scores (with padding) ----------------
__global__ __launch_bounds__(256) void k_write(const float* __restrict__ sboxes,
                                               const float* __restrict__ sscores,
                                               const unsigned int* __restrict__ keep,
                                               const unsigned int* __restrict__ keep_count,
                                               float* __restrict__ rois,
                                               float* __restrict__ rsc) {
  const int b = blockIdx.y;
  const int i = blockIdx.x * blockDim.x + threadIdx.x;
  if (i >= POST_K) return;
  const unsigned int K = keep_count[b];
  float4 bx;
  float s;
  if ((unsigned int)i < K) {
    unsigned int j = keep[b * POST_K + i];
    bx = ((const float4*)sboxes)[(size_t)b * PRE_K + j];
    s = sscores[(size_t)b * PRE_K + j];
  } else {
    bx = ((const float4*)sboxes)[(size_t)b * PRE_K + 0];  // boxes[argmax of all -1] = boxes[0]
    s = -1.0f;
  }
  ((float4*)rois)[(size_t)b * POST_K + i] = bx;
  rsc[(size_t)b * POST_K + i] = s;
}

// ---------------- launch ----------------
extern "C" void kernel_launch(void* const* d_in, const int* in_sizes, int n_in,
                              void* d_out, int out_size, void* d_ws, size_t ws_size,
                              hipStream_t stream) {
  const float* feats    = (const float*)d_in[0];
  const float* img_info = (const float*)d_in[1];
  const float* w_cls    = (const float*)d_in[2];
  const float* b_cls    = (const float*)d_in[3];
  const float* w_reg    = (const float*)d_in[4];
  const float* b_reg    = (const float*)d_in[5];

  float* out = (float*)d_out;
  float* out_cls  = out;              // [2,208,336,3]  = 419328
  float* out_bbox = out + 419328;     // [2,208,336,12] = 1677312
  float* out_rois = out + 2096640;    // [2,1000,4]     = 8000
  float* out_rsc  = out + 2104640;    // [2,1000]       = 2000

  char* ws = (char*)d_ws;
  unsigned int* hist        = (unsigned int*)(ws + WS_HIST);
  unsigned int* hist2       = (unsigned int*)(ws + WS_HIST2);
  unsigned int* meta_T      = (unsigned int*)(ws + WS_META);
  unsigned int* meta_T24    = (unsigned int*)(ws + WS_META24);
  unsigned int* cand_count  = (unsigned int*)(ws + WS_CCNT);
  unsigned int* keep_count  = (unsigned int*)(ws + WS_KCNT);
  unsigned long long* cand  = (unsigned long long*)(ws + WS_CAND);
  float* sboxes             = (float*)(ws + WS_SBOX);
  float* sscores            = (float*)(ws + WS_SSC);
  unsigned int* keep        = (unsigned int*)(ws + WS_KEEP);
  unsigned long long* mask  = (unsigned long long*)(ws + WS_MASK);

  k_zero<<<(WS_ZERO_WORDS + 255) / 256, 256, 0, stream>>>((unsigned int*)ws, WS_ZERO_WORDS);
  k_head<<<2048, 256, 0, stream>>>(feats, w_cls, b_cls, w_reg, b_reg, out_cls, out_bbox);
  k_hist<<<dim3(128, NB), 256, 0, stream>>>(out_cls, hist);
  k_thresh<<<NB, 1024, 0, stream>>>(hist, meta_T);
  k_hist2<<<dim3(128, NB), 256, 0, stream>>>(out_cls, meta_T, hist2);
  k_thresh2<<<NB, 1024, 0, stream>>>(hist, hist2, meta_T, meta_T24);
  k_compact<<<dim3(128, NB), 256, 0, stream>>>(out_cls, meta_T24, cand_count, cand);
  k_sort<<<NB, 1024, 0, stream>>>(cand, cand_count, out_bbox, img_info, sboxes, sscores);
  k_mask<<<dim3(32, 32, NB), 64, 0, stream>>>(sboxes, mask);
  k_scan<<<NB, 64, 0, stream>>>(mask, keep, keep_count);
  k_write<<<dim3(4, NB), 256, 0, stream>>>(sboxes, sscores, keep, keep_count, out_rois, out_rsc);
}

// Round 4
// 548.586 us; speedup vs baseline: 1.4522x; 1.0056x over previous
//
#include <hip/hip_runtime.h>
#include <cstdint>
#include <cstddef>

// ---------------- problem constants ----------------
#define HH 208
#define WW 336
#define NA 3
#define NPER 209664      // H*W*A per image
#define NROWS 139776     // B*H*W
#define NB 2
#define PRE_K 2000
#define POST_K 1000
#define CAP 8192         // candidate capacity per image (power of 2 for bitonic)
#define MW 32            // 64-bit words per mask row (32*64 = 2048 >= 2000)
#define MROWS 2048
#define BBOX_CLIP_F 4.135166556742356f

// ---------------- ws layout (bytes) ----------------
// [0)      hist       : NB*4096*4   = 32768
// [32768)  hist2      : NB*4096*4   = 32768   -> 65536
// [65536)  meta_T     : NB*4
// [65544)  meta_T24   : NB*4
// [65552)  cand_count : NB*4
// [65568)  keepw      : NB*32*8     = 512     -> 66080
// [66080)  cand       : NB*CAP*8    = 131072  -> 197152
// [197152) sboxes     : NB*2000*4*4 = 64000   -> 261152
// [261152) sscores    : NB*2000*4   = 16000   -> 277152
// [277248) mask       : NB*2048*32*8= 1048576 -> 1325824
#define WS_HIST   0
#define WS_HIST2  32768
#define WS_META   65536
#define WS_META24 65544
#define WS_CCNT   65552
#define WS_KEEPW  65568
#define WS_CAND   66080
#define WS_SBOX   197152
#define WS_SSC    261152
#define WS_MASK   277248
#define WS_ZERO_WORDS 49288   // zero [0, 197152) as u32 (hist, hist2, meta, counts, keepw, cand)

// ---------------- helpers ----------------
__device__ __forceinline__ float sigmoidf_ref(float x) {
  return __fdiv_rn(1.0f, __fadd_rn(1.0f, expf(-x)));
}
__device__ __forceinline__ unsigned int score_u(float logit) {
  float s = sigmoidf_ref(logit);            // s in (0,1), sign bit 0
  return __float_as_uint(s) | 0x80000000u;  // orderable
}

// broadcast 64-bit value from lane l (uniform l) via v_readlane — no LDS round trip
__device__ __forceinline__ unsigned long long bcast64(unsigned long long v, int l) {
  unsigned int lo = (unsigned int)__builtin_amdgcn_readlane((int)(unsigned int)v, l);
  unsigned int hi = (unsigned int)__builtin_amdgcn_readlane((int)(unsigned int)(v >> 32), l);
  return ((unsigned long long)hi << 32) | lo;
}

// decode box for anchor n of image b; matches reference op-by-op (no FMA contraction)
__device__ __forceinline__ float4 decode_box(const float* __restrict__ bbox,
                                             int b, unsigned int n,
                                             float hmax, float wmax) {
  unsigned int a = n % 3u;
  unsigned int pix = n / 3u;
  unsigned int y = pix / (unsigned int)WW;
  unsigned int x = pix % (unsigned int)WW;
  float yc = ((float)y + 0.5f) * 4.0f;   // exact in f32
  float xc = ((float)x + 0.5f) * 4.0f;   // exact in f32
  float hx = (a == 0) ? 16.0f : ((a == 1) ? 22.4f : 11.2f);
  float hy = (a == 0) ? 16.0f : ((a == 1) ? 11.2f : 22.4f);
  float ay1 = __fsub_rn(yc, hy), ax1 = __fsub_rn(xc, hx);
  float ay2 = __fadd_rn(yc, hy), ax2 = __fadd_rn(xc, hx);
  float ah = __fsub_rn(ay2, ay1), aw = __fsub_rn(ax2, ax1);
  float acy = __fadd_rn(ay1, __fmul_rn(0.5f, ah));
  float acx = __fadd_rn(ax1, __fmul_rn(0.5f, aw));
  const float* d = bbox + ((size_t)b * NPER + n) * 4u;
  float dy = d[0], dx = d[1];
  float dh = fminf(fmaxf(d[2], -BBOX_CLIP_F), BBOX_CLIP_F);
  float dw = fminf(fmaxf(d[3], -BBOX_CLIP_F), BBOX_CLIP_F);
  float cy = __fadd_rn(__fmul_rn(dy, ah), acy);
  float cx = __fadd_rn(__fmul_rn(dx, aw), acx);
  float hh = __fmul_rn(expf(dh), ah);
  float wwv = __fmul_rn(expf(dw), aw);
  float y1 = __fsub_rn(cy, __fmul_rn(0.5f, hh));
  float x1 = __fsub_rn(cx, __fmul_rn(0.5f, wwv));
  float y2 = __fadd_rn(cy, __fmul_rn(0.5f, hh));
  float x2 = __fadd_rn(cx, __fmul_rn(0.5f, wwv));
  y1 = fminf(fmaxf(y1, 0.0f), hmax);
  x1 = fminf(fmaxf(x1, 0.0f), wmax);
  y2 = fminf(fmaxf(y2, 0.0f), hmax);
  x2 = fminf(fmaxf(x2, 0.0f), wmax);
  return make_float4(y1, x1, y2, x2);
}

// reference IoU, exact op order
__device__ __forceinline__ float iou_ref(float4 bi, float4 bj) {
  float yA = fmaxf(bi.x, bj.x);
  float xA = fmaxf(bi.y, bj.y);
  float yB = fminf(bi.z, bj.z);
  float xB = fminf(bi.w, bj.w);
  float inter = __fmul_rn(fmaxf(__fsub_rn(yB, yA), 0.0f),
                          fmaxf(__fsub_rn(xB, xA), 0.0f));
  float a1 = __fmul_rn(__fsub_rn(bi.z, bi.x), __fsub_rn(bi.w, bi.y));
  float a2 = __fmul_rn(__fsub_rn(bj.z, bj.x), __fsub_rn(bj.w, bj.y));
  float den = __fadd_rn(__fsub_rn(__fadd_rn(a1, a2), inter), 1e-8f);
  return __fdiv_rn(inter, den);
}

// ---------------- K0: zero ws prefix ----------------
__global__ void k_zero(unsigned int* __restrict__ p, int n) {
  int i = blockIdx.x * blockDim.x + threadIdx.x;
  if (i < n) p[i] = 0u;
}

// ---------------- K1: head GEMM (wave-per-row) ----------------
__global__ __launch_bounds__(256) void k_head(
    const float* __restrict__ feats, const float* __restrict__ w_cls,
    const float* __restrict__ b_cls, const float* __restrict__ w_reg,
    const float* __restrict__ b_reg, float* __restrict__ out_cls,
    float* __restrict__ out_bbox) {
  const int lane = threadIdx.x & 63;
  const int wid = blockIdx.x * (blockDim.x >> 6) + (threadIdx.x >> 6);
  const int nw = gridDim.x * (blockDim.x >> 6);
  const int k0 = lane << 2;
  float wc[4][3], wr[4][12];
#pragma unroll
  for (int kk = 0; kk < 4; ++kk) {
#pragma unroll
    for (int o = 0; o < 3; ++o) wc[kk][o] = w_cls[(k0 + kk) * 3 + o];
#pragma unroll
    for (int o = 0; o < 12; ++o) wr[kk][o] = w_reg[(k0 + kk) * 12 + o];
  }
  float bc[3], br[12];
#pragma unroll
  for (int o = 0; o < 3; ++o) bc[o] = b_cls[o];
#pragma unroll
  for (int o = 0; o < 12; ++o) br[o] = b_reg[o];

  for (int r = wid; r < NROWS; r += nw) {
    const float4 f4 = *(const float4*)(feats + (size_t)r * 256 + k0);
    const float fv[4] = {f4.x, f4.y, f4.z, f4.w};
    float acc[15];
#pragma unroll
    for (int o = 0; o < 15; ++o) acc[o] = 0.0f;
#pragma unroll
    for (int kk = 0; kk < 4; ++kk) {
#pragma unroll
      for (int o = 0; o < 3; ++o) acc[o] += fv[kk] * wc[kk][o];
#pragma unroll
      for (int o = 0; o < 12; ++o) acc[3 + o] += fv[kk] * wr[kk][o];
    }
#pragma unroll
    for (int off = 32; off >= 1; off >>= 1) {
#pragma unroll
      for (int o = 0; o < 15; ++o) acc[o] += __shfl_xor(acc[o], off, 64);
    }
    if (lane == 0) {
#pragma unroll
      for (int o = 0; o < 3; ++o) out_cls[(size_t)r * 3 + o] = acc[o] + bc[o];
#pragma unroll
      for (int o = 0; o < 12; ++o) out_bbox[(size_t)r * 12 + o] = acc[3 + o] + br[o];
    }
  }
}

// ---------------- K2: 12-bit prefix histogram (LDS-staged) ----------------
__global__ __launch_bounds__(256) void k_hist(const float* __restrict__ out_cls,
                                              unsigned int* __restrict__ hist) {
  const int b = blockIdx.y;
  __shared__ unsigned int h[4096];
  for (int i = threadIdx.x; i < 4096; i += blockDim.x) h[i] = 0u;
  __syncthreads();
  for (int i = blockIdx.x * blockDim.x + threadIdx.x; i < NPER;
       i += gridDim.x * blockDim.x) {
    unsigned int u = score_u(out_cls[(size_t)b * NPER + i]);
    atomicAdd(&h[u >> 20], 1u);
  }
  __syncthreads();
  for (int i = threadIdx.x; i < 4096; i += blockDim.x)
    if (h[i]) atomicAdd(&hist[b * 4096 + i], h[i]);
}

// ---------------- K3: coarse threshold bin scan (1 block / image) ----------------
__global__ __launch_bounds__(1024) void k_thresh(const unsigned int* __restrict__ hist,
                                                 unsigned int* __restrict__ meta_T) {
  const int b = blockIdx.x;
  const int t = threadIdx.x;
  __shared__ unsigned int sums[1024];
  unsigned int hb[4];
  unsigned int s = 0u;
#pragma unroll
  for (int q = 0; q < 4; ++q) {
    int bin = 4095 - (t * 4 + q);   // descending bins
    hb[q] = hist[b * 4096 + bin];
    s += hb[q];
  }
  sums[t] = s;
  __syncthreads();
  for (int off = 1; off < 1024; off <<= 1) {
    unsigned int v = (t >= off) ? sums[t - off] : 0u;
    __syncthreads();
    sums[t] += v;
    __syncthreads();
  }
  unsigned int excl = sums[t] - s;  // count in bins above my chunk
  if (excl < PRE_K && excl + s >= PRE_K) {
    unsigned int c = excl;
#pragma unroll
    for (int q = 0; q < 4; ++q) {
      c += hb[q];
      if (c >= PRE_K) { meta_T[b] = (unsigned int)(4095 - (t * 4 + q)); break; }
    }
  }
}

// ---------------- K3b: refine histogram (next 12 bits, items in bin T only) ----------------
__global__ __launch_bounds__(256) void k_hist2(const float* __restrict__ out_cls,
                                               const unsigned int* __restrict__ meta_T,
                                               unsigned int* __restrict__ hist2) {
  const int b = blockIdx.y;
  const unsigned int T = meta_T[b];
  __shared__ unsigned int h[4096];
  for (int i = threadIdx.x; i < 4096; i += blockDim.x) h[i] = 0u;
  __syncthreads();
  for (int i = blockIdx.x * blockDim.x + threadIdx.x; i < NPER;
       i += gridDim.x * blockDim.x) {
    unsigned int u = score_u(out_cls[(size_t)b * NPER + i]);
    if ((u >> 20) == T) atomicAdd(&h[(u >> 8) & 0xFFFu], 1u);
  }
  __syncthreads();
  for (int i = threadIdx.x; i < 4096; i += blockDim.x)
    if (h[i]) atomicAdd(&hist2[b * 4096 + i], h[i]);
}

// ---------------- K3c: refined 24-bit threshold (1 block / image) ----------------
__global__ __launch_bounds__(1024) void k_thresh2(const unsigned int* __restrict__ hist,
                                                  const unsigned int* __restrict__ hist2,
                                                  const unsigned int* __restrict__ meta_T,
                                                  unsigned int* __restrict__ meta_T24) {
  const int b = blockIdx.x;
  const int t = threadIdx.x;
  const unsigned int T = meta_T[b];
  __shared__ unsigned int sums[1024];
  __shared__ unsigned int c0s;
  unsigned int c0 = 0u;
  for (int i = t; i < 4096; i += 1024)
    if ((unsigned int)i > T) c0 += hist[b * 4096 + i];
  sums[t] = c0;
  __syncthreads();
  for (int off = 512; off > 0; off >>= 1) {
    if (t < off) sums[t] += sums[t + off];
    __syncthreads();
  }
  if (t == 0) c0s = sums[0];
  __syncthreads();
  const unsigned int C0 = c0s;
  __syncthreads();
  unsigned int hb[4];
  unsigned int s = 0u;
#pragma unroll
  for (int q = 0; q < 4; ++q) {
    int bin = 4095 - (t * 4 + q);
    hb[q] = hist2[b * 4096 + bin];
    s += hb[q];
  }
  sums[t] = s;
  __syncthreads();
  for (int off = 1; off < 1024; off <<= 1) {
    unsigned int v = (t >= off) ? sums[t - off] : 0u;
    __syncthreads();
    sums[t] += v;
    __syncthreads();
  }
  unsigned int excl = sums[t] - s;
  if (C0 + excl < PRE_K && C0 + excl + s >= PRE_K) {
    unsigned int c = C0 + excl;
#pragma unroll
    for (int q = 0; q < 4; ++q) {
      c += hb[q];
      if (c >= PRE_K) {
        meta_T24[b] = (T << 12) | (unsigned int)(4095 - (t * 4 + q));
        break;
      }
    }
  }
}

// ---------------- K4: compact candidates (24-bit threshold) ----------------
__global__ __launch_bounds__(256) void k_compact(const float* __restrict__ out_cls,
                                                 const unsigned int* __restrict__ meta_T24,
                                                 unsigned int* __restrict__ cand_count,
                                                 unsigned long long* __restrict__ cand) {
  const int b = blockIdx.y;
  const unsigned int T24 = meta_T24[b];
  for (int i = blockIdx.x * blockDim.x + threadIdx.x; i < NPER;
       i += gridDim.x * blockDim.x) {
    unsigned int u = score_u(out_cls[(size_t)b * NPER + i]);
    if ((u >> 8) >= T24) {
      unsigned int pos = atomicAdd(&cand_count[b], 1u);
      if (pos < CAP)
        cand[(size_t)b * CAP + pos] =
            ((unsigned long long)u << 32) | (unsigned int)(~(unsigned int)i);
    }
  }
}

// ---------------- K5: adaptive bitonic sort (desc) + gather/decode top-2000 ----------------
// 256 threads (4 waves) — barrier cost at 16 waves dominated the 1024-thread version.
__global__ __launch_bounds__(256) void k_sort(const unsigned long long* __restrict__ cand,
                                              const unsigned int* __restrict__ cand_count,
                                              const float* __restrict__ out_bbox,
                                              const float* __restrict__ img_info,
                                              float* __restrict__ sboxes,
                                              float* __restrict__ sscores) {
  const int b = blockIdx.x;
  const int t = threadIdx.x;
  __shared__ unsigned long long keys[CAP];   // 64 KiB
  unsigned int cc = cand_count[b];
  if (cc > CAP) cc = CAP;
  int n = 2048;
  while ((unsigned int)n < cc) n <<= 1;
  for (int i = t; i < n; i += 256) keys[i] = cand[(size_t)b * CAP + i];
  __syncthreads();
  for (int k = 2; k <= n; k <<= 1) {
    for (int j = k >> 1; j > 0; j >>= 1) {
      for (int i = t; i < n; i += 256) {
        int ixj = i ^ j;
        if (ixj > i) {
          unsigned long long a = keys[i], c = keys[ixj];
          bool up = ((i & k) == 0);
          bool sw = up ? (a < c) : (a > c);   // descending overall
          if (sw) { keys[i] = c; keys[ixj] = a; }
        }
      }
      __syncthreads();
    }
  }
  const float hmax = img_info[b * 2 + 0];
  const float wmax = img_info[b * 2 + 1];
  for (int i = t; i < PRE_K; i += 256) {
    unsigned long long key = keys[i];
    unsigned int u = (unsigned int)(key >> 32);
    unsigned int idx = ~(unsigned int)(key & 0xFFFFFFFFull);
    float sc = __uint_as_float(u & 0x7FFFFFFFu);
    float4 bx = decode_box(out_bbox, b, idx, hmax, wmax);
    ((float4*)sboxes)[(size_t)b * PRE_K + i] = bx;
    sscores[(size_t)b * PRE_K + i] = sc;
  }
}

// ---------------- K6: pairwise suppression mask ----------------
__global__ __launch_bounds__(64) void k_mask(const float* __restrict__ sboxes,
                                             unsigned long long* __restrict__ mask) {
  const int b = blockIdx.z;
  const int rb = blockIdx.x;
  const int cb = blockIdx.y;
  const int t = threadIdx.x;
  __shared__ float4 cbox[64];
  const int col0 = cb * 64;
  {
    int c = col0 + t;
    cbox[t] = (c < PRE_K) ? ((const float4*)sboxes)[(size_t)b * PRE_K + c]
                          : make_float4(0.f, 0.f, 0.f, 0.f);
  }
  __syncthreads();
  const int i = rb * 64 + t;
  if (i >= PRE_K) return;
  float4 bi = ((const float4*)sboxes)[(size_t)b * PRE_K + i];
  unsigned long long bits = 0ull;
#pragma unroll 8
  for (int j = 0; j < 64; ++j) {
    int c = col0 + j;
    if (c > i && c < PRE_K) {
      if (iou_ref(bi, cbox[j]) > 0.7f) bits |= (1ull << j);
    }
  }
  mask[((size_t)b * MROWS + i) * MW + cb] = bits;
}

// ---------------- K7: scalar-pipe keep scan ----------------
// Group of 64 rows per step. Serial state:
//  w    (wave-uniform u64, SGPR): live suppression word for current group.
//  remv (per-lane u64): lane l accumulates mask word (l&31) from kept rows of
//        parity (l>>5) within their group; combined at group boundary via
//        v_readlane (no LDS round trip in the chain).
// Per-row cost: scalar bit-test (~5cy); kept row adds 2 readlanes + s_or.
// m-words prefetched one group ahead via fully-coalesced pair loads:
//   M[base*32 + 64k + lane] covers rows base+2k, base+2k+1 (512B/inst).
#define MLOAD(BUF, G)                                                     \
  {                                                                       \
    _Pragma("unroll") for (int _k = 0; _k < 32; ++_k) {                   \
      int _row = (G) * 64 + 2 * _k + psel;                                \
      (BUF)[_k] = (_row < PRE_K) ? M[(size_t)(G) * 2048 + 64 * _k + lane] \
                                 : 0ull;                                  \
    }                                                                     \
  }
#define DLOAD(DST, G)                                                     \
  {                                                                       \
    int _row = (G) * 64 + lane;                                           \
    (DST) = ((G) < 32 && _row < PRE_K) ? M[(size_t)_row * MW + (G)] : 0ull; \
  }
#define GSTEP(G, MCUR, MNEXT, DCUR, DNEXT)                                \
  do {                                                                    \
    MLOAD(MNEXT, (G) + 1);                                                \
    DLOAD(DNEXT, (G) + 1);                                                \
    unsigned long long w = bcast64(remv, (G)) | bcast64(remv, (G) + 32);  \
    unsigned long long kept = 0ull;                                       \
    const int rowlim = ((G) + 1) * 64 <= PRE_K ? 64 : (PRE_K - (G) * 64); \
    for (int j = 0; j < rowlim; ++j) {                                    \
      if (!((w >> j) & 1ull)) {                                           \
        if (nk >= POST_K) { stop = 1; break; }                            \
        ++nk;                                                             \
        kept |= (1ull << j);                                              \
        w |= bcast64((DCUR), j);                                          \
      }                                                                   \
    }                                                                     \
    if (lane == 0) keepw[b * 32 + (G)] = kept;                            \
    if (!stop) {                                                          \
      unsigned long long keptv = kept >> psel;                            \
      _Pragma("unroll") for (int _q = 0; _q < 32; ++_q) {                 \
        unsigned long long sel = 0ull - ((keptv >> (2 * _q)) & 1ull);     \
        remv |= (MCUR)[_q] & sel;                                         \
      }                                                                   \
    }                                                                     \
  } while (0)

__global__ __launch_bounds__(64, 1) void k_scan(
    const unsigned long long* __restrict__ mask,
    unsigned long long* __restrict__ keepw) {
  const int b = blockIdx.x;
  const int lane = threadIdx.x;
  const int psel = lane >> 5;   // row parity this lane covers in pair loads
  const unsigned long long* M = mask + (size_t)b * MROWS * MW;

  unsigned long long mbA[32], mbB[32], dA, dB;
  unsigned long long remv = 0ull;
  int nk = 0, stop = 0;

  MLOAD(mbA, 0);
  DLOAD(dA, 0);
  for (int g = 0; g < 32; g += 2) {
    GSTEP(g, mbA, mbB, dA, dB);
    if (stop) break;
    GSTEP(g + 1, mbB, mbA, dB, dA);
    if (stop) break;
  }
}

// ---------------- K8: rank reconstruction + write rois / roi_scores ----------------
__global__ __launch_bounds__(64) void k_write(const float* __restrict__ sboxes,
                                              const float* __restrict__ sscores,
                                              const unsigned long long* __restrict__ keepw,
                                              float* __restrict__ rois,
                                              float* __restrict__ rsc) {
  const int b = blockIdx.x;
  const int lane = threadIdx.x;
  unsigned long long w = (lane < 32) ? keepw[b * 32 + lane] : 0ull;
  int pc = __popcll(w);
  int pref = pc;
#pragma unroll
  for (int off = 1; off < 64; off <<= 1) {
    int v = __shfl_up(pref, off, 64);
    if (lane >= off) pref += v;
  }
  const int excl = pref - pc;
  const int Ktot = __shfl(pref, 63, 64);
  // scatter kept rows to their ranks (rows ascending == greedy order)
  int rank = excl;
  unsigned long long ww = w;
  while (ww) {
    int j = __builtin_ctzll(ww);
    ww &= ww - 1;
    int row = lane * 64 + j;
    ((float4*)rois)[(size_t)b * POST_K + rank] =
        ((const float4*)sboxes)[(size_t)b * PRE_K + row];
    rsc[(size_t)b * POST_K + rank] = sscores[(size_t)b * PRE_K + row];
    ++rank;
  }
  // padding: boxes[argmax of all -1] = boxes[0], score -1
  float4 pad = ((const float4*)sboxes)[(size_t)b * PRE_K + 0];
  for (int i = Ktot + lane; i < POST_K; i += 64) {
    ((float4*)rois)[(size_t)b * POST_K + i] = pad;
    rsc[(size_t)b * POST_K + i] = -1.0f;
  }
}

// ---------------- launch ----------------
extern "C" void kernel_launch(void* const* d_in, const int* in_sizes, int n_in,
                              void* d_out, int out_size, void* d_ws, size_t ws_size,
                              hipStream_t stream) {
  const float* feats    = (const float*)d_in[0];
  const float* img_info = (const float*)d_in[1];
  const float* w_cls    = (const float*)d_in[2];
  const float* b_cls    = (const float*)d_in[3];
  const float* w_reg    = (const float*)d_in[4];
  const float* b_reg    = (const float*)d_in[5];

  float* out = (float*)d_out;
  float* out_cls  = out;              // [2,208,336,3]  = 419328
  float* out_bbox = out + 419328;     // [2,208,336,12] = 1677312
  float* out_rois = out + 2096640;    // [2,1000,4]     = 8000
  float* out_rsc  = out + 2104640;    // [2,1000]       = 2000

  char* ws = (char*)d_ws;
  unsigned int* hist        = (unsigned int*)(ws + WS_HIST);
  unsigned int* hist2       = (unsigned int*)(ws + WS_HIST2);
  unsigned int* meta_T      = (unsigned int*)(ws + WS_META);
  unsigned int* meta_T24    = (unsigned int*)(ws + WS_META24);
  unsigned int* cand_count  = (unsigned int*)(ws + WS_CCNT);
  unsigned long long* keepw = (unsigned long long*)(ws + WS_KEEPW);
  unsigned long long* cand  = (unsigned long long*)(ws + WS_CAND);
  float* sboxes             = (float*)(ws + WS_SBOX);
  float* sscores            = (float*)(ws + WS_SSC);
  unsigned long long* mask  = (unsigned long long*)(ws + WS_MASK);

  k_zero<<<(WS_ZERO_WORDS + 255) / 256, 256, 0, stream>>>((unsigned int*)ws, WS_ZERO_WORDS);
  k_head<<<2048, 256, 0, stream>>>(feats, w_cls, b_cls, w_reg, b_reg, out_cls, out_bbox);
  k_hist<<<dim3(128, NB), 256, 0, stream>>>(out_cls, hist);
  k_thresh<<<NB, 1024, 0, stream>>>(hist, meta_T);
  k_hist2<<<dim3(128, NB), 256, 0, stream>>>(out_cls, meta_T, hist2);
  k_thresh2<<<NB, 1024, 0, stream>>>(hist, hist2, meta_T, meta_T24);
  k_compact<<<dim3(128, NB), 256, 0, stream>>>(out_cls, meta_T24, cand_count, cand);
  k_sort<<<NB, 256, 0, stream>>>(cand, cand_count, out_bbox, img_info, sboxes, sscores);
  k_mask<<<dim3(32, 32, NB), 64, 0, stream>>>(sboxes, mask);
  k_scan<<<NB, 64, 0, stream>>>(mask, keepw);
  k_write<<<NB, 64, 0, stream>>>(sboxes, sscores, keepw, out_rois, out_rsc);
}

// Round 5
// 482.170 us; speedup vs baseline: 1.6522x; 1.1377x over previous
//
#include <hip/hip_runtime.h>
#include <cstdint>
#include <cstddef>

// ---------------- problem constants ----------------
#define HH 208
#define WW 336
#define NA 3
#define NPER 209664      // H*W*A per image
#define NROWS 139776     // B*H*W
#define NB 2
#define PRE_K 2000
#define POST_K 1000
#define CAP 8192         // candidate capacity per image (power of 2 for bitonic)
#define MW 32            // 64-bit words per mask row (32*64 = 2048 >= 2000)
#define MROWS 2048
#define BBOX_CLIP_F 4.135166556742356f

// ---------------- ws layout (bytes) ----------------
#define WS_HIST   0
#define WS_HIST2  32768
#define WS_META   65536
#define WS_META24 65544
#define WS_CCNT   65552
#define WS_KEEPW  65568
#define WS_CAND   66080
#define WS_SBOX   197152
#define WS_SSC    261152
#define WS_MASK   277248
#define WS_ZERO_WORDS 49288   // zero [0, 197152) as u32 (hist, hist2, meta, counts, keepw, cand)

// ---------------- helpers ----------------
__device__ __forceinline__ float sigmoidf_ref(float x) {
  return __fdiv_rn(1.0f, __fadd_rn(1.0f, expf(-x)));
}
__device__ __forceinline__ unsigned int score_u(float logit) {
  float s = sigmoidf_ref(logit);            // s in (0,1), sign bit 0
  return __float_as_uint(s) | 0x80000000u;  // orderable
}

// broadcast 64-bit value from lane l (uniform l) via v_readlane — no LDS round trip
__device__ __forceinline__ unsigned long long bcast64(unsigned long long v, int l) {
  unsigned int lo = (unsigned int)__builtin_amdgcn_readlane((int)(unsigned int)v, l);
  unsigned int hi = (unsigned int)__builtin_amdgcn_readlane((int)(unsigned int)(v >> 32), l);
  return ((unsigned long long)hi << 32) | lo;
}

// decode box for anchor n of image b; matches reference op-by-op (no FMA contraction)
__device__ __forceinline__ float4 decode_box(const float* __restrict__ bbox,
                                             int b, unsigned int n,
                                             float hmax, float wmax) {
  unsigned int a = n % 3u;
  unsigned int pix = n / 3u;
  unsigned int y = pix / (unsigned int)WW;
  unsigned int x = pix % (unsigned int)WW;
  float yc = ((float)y + 0.5f) * 4.0f;   // exact in f32
  float xc = ((float)x + 0.5f) * 4.0f;   // exact in f32
  float hx = (a == 0) ? 16.0f : ((a == 1) ? 22.4f : 11.2f);
  float hy = (a == 0) ? 16.0f : ((a == 1) ? 11.2f : 22.4f);
  float ay1 = __fsub_rn(yc, hy), ax1 = __fsub_rn(xc, hx);
  float ay2 = __fadd_rn(yc, hy), ax2 = __fadd_rn(xc, hx);
  float ah = __fsub_rn(ay2, ay1), aw = __fsub_rn(ax2, ax1);
  float acy = __fadd_rn(ay1, __fmul_rn(0.5f, ah));
  float acx = __fadd_rn(ax1, __fmul_rn(0.5f, aw));
  const float* d = bbox + ((size_t)b * NPER + n) * 4u;
  float dy = d[0], dx = d[1];
  float dh = fminf(fmaxf(d[2], -BBOX_CLIP_F), BBOX_CLIP_F);
  float dw = fminf(fmaxf(d[3], -BBOX_CLIP_F), BBOX_CLIP_F);
  float cy = __fadd_rn(__fmul_rn(dy, ah), acy);
  float cx = __fadd_rn(__fmul_rn(dx, aw), acx);
  float hh = __fmul_rn(expf(dh), ah);
  float wwv = __fmul_rn(expf(dw), aw);
  float y1 = __fsub_rn(cy, __fmul_rn(0.5f, hh));
  float x1 = __fsub_rn(cx, __fmul_rn(0.5f, wwv));
  float y2 = __fadd_rn(cy, __fmul_rn(0.5f, hh));
  float x2 = __fadd_rn(cx, __fmul_rn(0.5f, wwv));
  y1 = fminf(fmaxf(y1, 0.0f), hmax);
  x1 = fminf(fmaxf(x1, 0.0f), wmax);
  y2 = fminf(fmaxf(y2, 0.0f), hmax);
  x2 = fminf(fmaxf(x2, 0.0f), wmax);
  return make_float4(y1, x1, y2, x2);
}

// reference IoU, exact op order
__device__ __forceinline__ float iou_ref(float4 bi, float4 bj) {
  float yA = fmaxf(bi.x, bj.x);
  float xA = fmaxf(bi.y, bj.y);
  float yB = fminf(bi.z, bj.z);
  float xB = fminf(bi.w, bj.w);
  float inter = __fmul_rn(fmaxf(__fsub_rn(yB, yA), 0.0f),
                          fmaxf(__fsub_rn(xB, xA), 0.0f));
  float a1 = __fmul_rn(__fsub_rn(bi.z, bi.x), __fsub_rn(bi.w, bi.y));
  float a2 = __fmul_rn(__fsub_rn(bj.z, bj.x), __fsub_rn(bj.w, bj.y));
  float den = __fadd_rn(__fsub_rn(__fadd_rn(a1, a2), inter), 1e-8f);
  return __fdiv_rn(inter, den);
}

// ---------------- K0: zero ws prefix ----------------
__global__ void k_zero(unsigned int* __restrict__ p, int n) {
  int i = blockIdx.x * blockDim.x + threadIdx.x;
  if (i < n) p[i] = 0u;
}

// ---------------- K1: head GEMM, xor-aligned slot reduction ----------------
// Lane l's slot j holds output (brev4(l&15) ^ j). Then every butterfly level
// is a[s] += shfl_xor(a[half+s], bit) with NO per-lane selects:
// 17 shuffles total vs 90 for the naive 15-acc tree. Lane l<16 ends holding
// output brev4(l&15); permutation folded into the one-time weight load.
__global__ __launch_bounds__(256) void k_head(
    const float* __restrict__ feats, const float* __restrict__ w_cls,
    const float* __restrict__ b_cls, const float* __restrict__ w_reg,
    const float* __restrict__ b_reg, float* __restrict__ out_cls,
    float* __restrict__ out_bbox) {
  const int lane = threadIdx.x & 63;
  const int wid = blockIdx.x * (blockDim.x >> 6) + (threadIdx.x >> 6);
  const int nw = gridDim.x * (blockDim.x >> 6);
  const int k0 = lane << 2;
  const int l15 = lane & 15;
  const int ol = ((l15 & 1) << 3) | ((l15 & 2) << 1) | ((l15 & 4) >> 1) |
                 ((l15 & 8) >> 3);  // brev4 — this lane's final output

  float wreg[4][16];
#pragma unroll
  for (int j = 0; j < 16; ++j) {
    const int o = ol ^ j;
#pragma unroll
    for (int kk = 0; kk < 4; ++kk) {
      wreg[kk][j] = (o < 3) ? w_cls[(k0 + kk) * 3 + o]
                            : (o < 15 ? w_reg[(k0 + kk) * 12 + (o - 3)] : 0.0f);
    }
  }
  const float bias = (ol < 3) ? b_cls[ol] : (ol < 15 ? b_reg[ol - 3] : 0.0f);

  for (int r = wid; r < NROWS; r += nw) {
    const float4 f4 = *(const float4*)(feats + (size_t)r * 256 + k0);
    float a[16];
#pragma unroll
    for (int j = 0; j < 16; ++j) {
      a[j] = f4.x * wreg[0][j];
      a[j] += f4.y * wreg[1][j];
      a[j] += f4.z * wreg[2][j];
      a[j] += f4.w * wreg[3][j];
    }
#pragma unroll
    for (int s = 0; s < 8; ++s) a[s] += __shfl_xor(a[8 + s], 1, 64);
#pragma unroll
    for (int s = 0; s < 4; ++s) a[s] += __shfl_xor(a[4 + s], 2, 64);
#pragma unroll
    for (int s = 0; s < 2; ++s) a[s] += __shfl_xor(a[2 + s], 4, 64);
    a[0] += __shfl_xor(a[1], 8, 64);
    a[0] += __shfl_xor(a[0], 16, 64);
    a[0] += __shfl_xor(a[0], 32, 64);
    if (lane < 16 && ol < 15) {
      float v = a[0] + bias;
      if (ol < 3) out_cls[(size_t)r * 3 + ol] = v;
      else        out_bbox[(size_t)r * 12 + (ol - 3)] = v;
    }
  }
}

// ---------------- K2: 12-bit prefix histogram (LDS-staged) ----------------
__global__ __launch_bounds__(256) void k_hist(const float* __restrict__ out_cls,
                                              unsigned int* __restrict__ hist) {
  const int b = blockIdx.y;
  __shared__ unsigned int h[4096];
  for (int i = threadIdx.x; i < 4096; i += blockDim.x) h[i] = 0u;
  __syncthreads();
  for (int i = blockIdx.x * blockDim.x + threadIdx.x; i < NPER;
       i += gridDim.x * blockDim.x) {
    unsigned int u = score_u(out_cls[(size_t)b * NPER + i]);
    atomicAdd(&h[u >> 20], 1u);
  }
  __syncthreads();
  for (int i = threadIdx.x; i < 4096; i += blockDim.x)
    if (h[i]) atomicAdd(&hist[b * 4096 + i], h[i]);
}

// ---------------- K3: coarse threshold bin scan (1 block / image) ----------------
__global__ __launch_bounds__(1024) void k_thresh(const unsigned int* __restrict__ hist,
                                                 unsigned int* __restrict__ meta_T) {
  const int b = blockIdx.x;
  const int t = threadIdx.x;
  __shared__ unsigned int sums[1024];
  unsigned int hb[4];
  unsigned int s = 0u;
#pragma unroll
  for (int q = 0; q < 4; ++q) {
    int bin = 4095 - (t * 4 + q);   // descending bins
    hb[q] = hist[b * 4096 + bin];
    s += hb[q];
  }
  sums[t] = s;
  __syncthreads();
  for (int off = 1; off < 1024; off <<= 1) {
    unsigned int v = (t >= off) ? sums[t - off] : 0u;
    __syncthreads();
    sums[t] += v;
    __syncthreads();
  }
  unsigned int excl = sums[t] - s;  // count in bins above my chunk
  if (excl < PRE_K && excl + s >= PRE_K) {
    unsigned int c = excl;
#pragma unroll
    for (int q = 0; q < 4; ++q) {
      c += hb[q];
      if (c >= PRE_K) { meta_T[b] = (unsigned int)(4095 - (t * 4 + q)); break; }
    }
  }
}

// ---------------- K3b: refine histogram (next 12 bits, items in bin T only) ----------------
__global__ __launch_bounds__(256) void k_hist2(const float* __restrict__ out_cls,
                                               const unsigned int* __restrict__ meta_T,
                                               unsigned int* __restrict__ hist2) {
  const int b = blockIdx.y;
  const unsigned int T = meta_T[b];
  __shared__ unsigned int h[4096];
  for (int i = threadIdx.x; i < 4096; i += blockDim.x) h[i] = 0u;
  __syncthreads();
  for (int i = blockIdx.x * blockDim.x + threadIdx.x; i < NPER;
       i += gridDim.x * blockDim.x) {
    unsigned int u = score_u(out_cls[(size_t)b * NPER + i]);
    if ((u >> 20) == T) atomicAdd(&h[(u >> 8) & 0xFFFu], 1u);
  }
  __syncthreads();
  for (int i = threadIdx.x; i < 4096; i += blockDim.x)
    if (h[i]) atomicAdd(&hist2[b * 4096 + i], h[i]);
}

// ---------------- K3c: refined 24-bit threshold (1 block / image) ----------------
__global__ __launch_bounds__(1024) void k_thresh2(const unsigned int* __restrict__ hist,
                                                  const unsigned int* __restrict__ hist2,
                                                  const unsigned int* __restrict__ meta_T,
                                                  unsigned int* __restrict__ meta_T24) {
  const int b = blockIdx.x;
  const int t = threadIdx.x;
  const unsigned int T = meta_T[b];
  __shared__ unsigned int sums[1024];
  __shared__ unsigned int c0s;
  unsigned int c0 = 0u;
  for (int i = t; i < 4096; i += 1024)
    if ((unsigned int)i > T) c0 += hist[b * 4096 + i];
  sums[t] = c0;
  __syncthreads();
  for (int off = 512; off > 0; off >>= 1) {
    if (t < off) sums[t] += sums[t + off];
    __syncthreads();
  }
  if (t == 0) c0s = sums[0];
  __syncthreads();
  const unsigned int C0 = c0s;
  __syncthreads();
  unsigned int hb[4];
  unsigned int s = 0u;
#pragma unroll
  for (int q = 0; q < 4; ++q) {
    int bin = 4095 - (t * 4 + q);
    hb[q] = hist2[b * 4096 + bin];
    s += hb[q];
  }
  sums[t] = s;
  __syncthreads();
  for (int off = 1; off < 1024; off <<= 1) {
    unsigned int v = (t >= off) ? sums[t - off] : 0u;
    __syncthreads();
    sums[t] += v;
    __syncthreads();
  }
  unsigned int excl = sums[t] - s;
  if (C0 + excl < PRE_K && C0 + excl + s >= PRE_K) {
    unsigned int c = C0 + excl;
#pragma unroll
    for (int q = 0; q < 4; ++q) {
      c += hb[q];
      if (c >= PRE_K) {
        meta_T24[b] = (T << 12) | (unsigned int)(4095 - (t * 4 + q));
        break;
      }
    }
  }
}

// ---------------- K4: compact candidates (24-bit threshold) ----------------
__global__ __launch_bounds__(256) void k_compact(const float* __restrict__ out_cls,
                                                 const unsigned int* __restrict__ meta_T24,
                                                 unsigned int* __restrict__ cand_count,
                                                 unsigned long long* __restrict__ cand) {
  const int b = blockIdx.y;
  const unsigned int T24 = meta_T24[b];
  for (int i = blockIdx.x * blockDim.x + threadIdx.x; i < NPER;
       i += gridDim.x * blockDim.x) {
    unsigned int u = score_u(out_cls[(size_t)b * NPER + i]);
    if ((u >> 8) >= T24) {
      unsigned int pos = atomicAdd(&cand_count[b], 1u);
      if (pos < CAP)
        cand[(size_t)b * CAP + pos] =
            ((unsigned long long)u << 32) | (unsigned int)(~(unsigned int)i);
    }
  }
}

// ---------------- K5: adaptive bitonic sort (desc) + gather/decode top-2000 ----------------
__global__ __launch_bounds__(256) void k_sort(const unsigned long long* __restrict__ cand,
                                              const unsigned int* __restrict__ cand_count,
                                              const float* __restrict__ out_bbox,
                                              const float* __restrict__ img_info,
                                              float* __restrict__ sboxes,
                                              float* __restrict__ sscores) {
  const int b = blockIdx.x;
  const int t = threadIdx.x;
  __shared__ unsigned long long keys[CAP];   // 64 KiB
  unsigned int cc = cand_count[b];
  if (cc > CAP) cc = CAP;
  int n = 2048;
  while ((unsigned int)n < cc) n <<= 1;
  for (int i = t; i < n; i += 256) keys[i] = cand[(size_t)b * CAP + i];
  __syncthreads();
  for (int k = 2; k <= n; k <<= 1) {
    for (int j = k >> 1; j > 0; j >>= 1) {
      for (int i = t; i < n; i += 256) {
        int ixj = i ^ j;
        if (ixj > i) {
          unsigned long long a = keys[i], c = keys[ixj];
          bool up = ((i & k) == 0);
          bool sw = up ? (a < c) : (a > c);   // descending overall
          if (sw) { keys[i] = c; keys[ixj] = a; }
        }
      }
      __syncthreads();
    }
  }
  const float hmax = img_info[b * 2 + 0];
  const float wmax = img_info[b * 2 + 1];
  for (int i = t; i < PRE_K; i += 256) {
    unsigned long long key = keys[i];
    unsigned int u = (unsigned int)(key >> 32);
    unsigned int idx = ~(unsigned int)(key & 0xFFFFFFFFull);
    float sc = __uint_as_float(u & 0x7FFFFFFFu);
    float4 bx = decode_box(out_bbox, b, idx, hmax, wmax);
    ((float4*)sboxes)[(size_t)b * PRE_K + i] = bx;
    sscores[(size_t)b * PRE_K + i] = sc;
  }
}

// ---------------- K6: pairwise suppression mask ----------------
__global__ __launch_bounds__(64) void k_mask(const float* __restrict__ sboxes,
                                             unsigned long long* __restrict__ mask) {
  const int b = blockIdx.z;
  const int rb = blockIdx.x;
  const int cb = blockIdx.y;
  const int t = threadIdx.x;
  __shared__ float4 cbox[64];
  const int col0 = cb * 64;
  {
    int c = col0 + t;
    cbox[t] = (c < PRE_K) ? ((const float4*)sboxes)[(size_t)b * PRE_K + c]
                          : make_float4(0.f, 0.f, 0.f, 0.f);
  }
  __syncthreads();
  const int i = rb * 64 + t;
  if (i >= PRE_K) return;
  float4 bi = ((const float4*)sboxes)[(size_t)b * PRE_K + i];
  unsigned long long bits = 0ull;
#pragma unroll 8
  for (int j = 0; j < 64; ++j) {
    int c = col0 + j;
    if (c > i && c < PRE_K) {
      if (iou_ref(bi, cbox[j]) > 0.7f) bits |= (1ull << j);
    }
  }
  mask[((size_t)b * MROWS + i) * MW + cb] = bits;
}

// ---------------- K7: scalar-pipe keep scan ----------------
#define MLOAD(BUF, G)                                                     \
  {                                                                       \
    _Pragma("unroll") for (int _k = 0; _k < 32; ++_k) {                   \
      int _row = (G) * 64 + 2 * _k + psel;                                \
      (BUF)[_k] = (_row < PRE_K) ? M[(size_t)(G) * 2048 + 64 * _k + lane] \
                                 : 0ull;                                  \
    }                                                                     \
  }
#define DLOAD(DST, G)                                                     \
  {                                                                       \
    int _row = (G) * 64 + lane;                                           \
    (DST) = ((G) < 32 && _row < PRE_K) ? M[(size_t)_row * MW + (G)] : 0ull; \
  }
#define GSTEP(G, MCUR, MNEXT, DCUR, DNEXT)                                \
  do {                                                                    \
    MLOAD(MNEXT, (G) + 1);                                                \
    DLOAD(DNEXT, (G) + 1);                                                \
    unsigned long long w = bcast64(remv, (G)) | bcast64(remv, (G) + 32);  \
    unsigned long long kept = 0ull;                                       \
    const int rowlim = ((G) + 1) * 64 <= PRE_K ? 64 : (PRE_K - (G) * 64); \
    for (int j = 0; j < rowlim; ++j) {                                    \
      if (!((w >> j) & 1ull)) {                                           \
        if (nk >= POST_K) { stop = 1; break; }                            \
        ++nk;                                                             \
        kept |= (1ull << j);                                              \
        w |= bcast64((DCUR), j);                                          \
      }                                                                   \
    }                                                                     \
    if (lane == 0) keepw[b * 32 + (G)] = kept;                            \
    if (!stop) {                                                          \
      unsigned long long keptv = kept >> psel;                            \
      _Pragma("unroll") for (int _q = 0; _q < 32; ++_q) {                 \
        unsigned long long sel = 0ull - ((keptv >> (2 * _q)) & 1ull);     \
        remv |= (MCUR)[_q] & sel;                                         \
      }                                                                   \
    }                                                                     \
  } while (0)

__global__ __launch_bounds__(64, 1) void k_scan(
    const unsigned long long* __restrict__ mask,
    unsigned long long* __restrict__ keepw) {
  const int b = blockIdx.x;
  const int lane = threadIdx.x;
  const int psel = lane >> 5;   // row parity this lane covers in pair loads
  const unsigned long long* M = mask + (size_t)b * MROWS * MW;

  unsigned long long mbA[32], mbB[32], dA, dB;
  unsigned long long remv = 0ull;
  int nk = 0, stop = 0;

  MLOAD(mbA, 0);
  DLOAD(dA, 0);
  for (int g = 0; g < 32; g += 2) {
    GSTEP(g, mbA, mbB, dA, dB);
    if (stop) break;
    GSTEP(g + 1, mbB, mbA, dB, dA);
    if (stop) break;
  }
}

// ---------------- K8: rank reconstruction + write rois / roi_scores ----------------
__global__ __launch_bounds__(64) void k_write(const float* __restrict__ sboxes,
                                              const float* __restrict__ sscores,
                                              const unsigned long long* __restrict__ keepw,
                                              float* __restrict__ rois,
                                              float* __restrict__ rsc) {
  const int b = blockIdx.x;
  const int lane = threadIdx.x;
  unsigned long long w = (lane < 32) ? keepw[b * 32 + lane] : 0ull;
  int pc = __popcll(w);
  int pref = pc;
#pragma unroll
  for (int off = 1; off < 64; off <<= 1) {
    int v = __shfl_up(pref, off, 64);
    if (lane >= off) pref += v;
  }
  const int excl = pref - pc;
  const int Ktot = __shfl(pref, 63, 64);
  int rank = excl;
  unsigned long long ww = w;
  while (ww) {
    int j = __builtin_ctzll(ww);
    ww &= ww - 1;
    int row = lane * 64 + j;
    ((float4*)rois)[(size_t)b * POST_K + rank] =
        ((const float4*)sboxes)[(size_t)b * PRE_K + row];
    rsc[(size_t)b * POST_K + rank] = sscores[(size_t)b * PRE_K + row];
    ++rank;
  }
  float4 pad = ((const float4*)sboxes)[(size_t)b * PRE_K + 0];
  for (int i = Ktot + lane; i < POST_K; i += 64) {
    ((float4*)rois)[(size_t)b * POST_K + i] = pad;
    rsc[(size_t)b * POST_K + i] = -1.0f;
  }
}

// ---------------- launch ----------------
extern "C" void kernel_launch(void* const* d_in, const int* in_sizes, int n_in,
                              void* d_out, int out_size, void* d_ws, size_t ws_size,
                              hipStream_t stream) {
  const float* feats    = (const float*)d_in[0];
  const float* img_info = (const float*)d_in[1];
  const float* w_cls    = (const float*)d_in[2];
  const float* b_cls    = (const float*)d_in[3];
  const float* w_reg    = (const float*)d_in[4];
  const float* b_reg    = (const float*)d_in[5];

  float* out = (float*)d_out;
  float* out_cls  = out;              // [2,208,336,3]  = 419328
  float* out_bbox = out + 419328;     // [2,208,336,12] = 1677312
  float* out_rois = out + 2096640;    // [2,1000,4]     = 8000
  float* out_rsc  = out + 2104640;    // [2,1000]       = 2000

  char* ws = (char*)d_ws;
  unsigned int* hist        = (unsigned int*)(ws + WS_HIST);
  unsigned int* hist2       = (unsigned int*)(ws + WS_HIST2);
  unsigned int* meta_T      = (unsigned int*)(ws + WS_META);
  unsigned int* meta_T24    = (unsigned int*)(ws + WS_META24);
  unsigned int* cand_count  = (unsigned int*)(ws + WS_CCNT);
  unsigned long long* keepw = (unsigned long long*)(ws + WS_KEEPW);
  unsigned long long* cand  = (unsigned long long*)(ws + WS_CAND);
  float* sboxes             = (float*)(ws + WS_SBOX);
  float* sscores            = (float*)(ws + WS_SSC);
  unsigned long long* mask  = (unsigned long long*)(ws + WS_MASK);

  k_zero<<<(WS_ZERO_WORDS + 255) / 256, 256, 0, stream>>>((unsigned int*)ws, WS_ZERO_WORDS);
  k_head<<<2048, 256, 0, stream>>>(feats, w_cls, b_cls, w_reg, b_reg, out_cls, out_bbox);
  k_hist<<<dim3(128, NB), 256, 0, stream>>>(out_cls, hist);
  k_thresh<<<NB, 1024, 0, stream>>>(hist, meta_T);
  k_hist2<<<dim3(128, NB), 256, 0, stream>>>(out_cls, meta_T, hist2);
  k_thresh2<<<NB, 1024, 0, stream>>>(hist, hist2, meta_T, meta_T24);
  k_compact<<<dim3(128, NB), 256, 0, stream>>>(out_cls, meta_T24, cand_count, cand);
  k_sort<<<NB, 256, 0, stream>>>(cand, cand_count, out_bbox, img_info, sboxes, sscores);
  k_mask<<<dim3(32, 32, NB), 64, 0, stream>>>(sboxes, mask);
  k_scan<<<NB, 64, 0, stream>>>(mask, keepw);
  k_write<<<NB, 64, 0, stream>>>(sboxes, sscores, keepw, out_rois, out_rsc);
}

// Round 6
// 413.973 us; speedup vs baseline: 1.9244x; 1.1647x over previous
//
#include <hip/hip_runtime.h>
#include <cstdint>
#include <cstddef>

// ---------------- problem constants ----------------
#define HH 208
#define WW 336
#define NA 3
#define NPER 209664      // H*W*A per image
#define NROWS 139776     // B*H*W
#define NB 2
#define PRE_K 2000
#define POST_K 1000
#define CAP 8192         // candidate capacity per image (power of 2 for bitonic)
#define MW 32            // 64-bit words per mask row (32*64 = 2048 >= 2000)
#define MROWS 2048
#define BBOX_CLIP_F 4.135166556742356f

// ---------------- ws layout (bytes) ----------------
#define WS_HIST   0
#define WS_HIST2  32768
#define WS_META   65536
#define WS_META24 65544
#define WS_CCNT   65552
#define WS_KEEPW  65568
#define WS_CAND   66080
#define WS_SBOX   197152
#define WS_SSC    261152
#define WS_MASK   277248
#define WS_ZERO_WORDS 49288   // zero [0, 197152) as u32 (hist, hist2, meta, counts, keepw, cand)

// ---------------- helpers ----------------
__device__ __forceinline__ float sigmoidf_ref(float x) {
  return __fdiv_rn(1.0f, __fadd_rn(1.0f, expf(-x)));
}
__device__ __forceinline__ unsigned int score_u(float logit) {
  float s = sigmoidf_ref(logit);            // s in (0,1), sign bit 0
  return __float_as_uint(s) | 0x80000000u;  // orderable
}

// broadcast 64-bit value from lane l (uniform l) via v_readlane — no LDS round trip
__device__ __forceinline__ unsigned long long bcast64(unsigned long long v, int l) {
  unsigned int lo = (unsigned int)__builtin_amdgcn_readlane((int)(unsigned int)v, l);
  unsigned int hi = (unsigned int)__builtin_amdgcn_readlane((int)(unsigned int)(v >> 32), l);
  return ((unsigned long long)hi << 32) | lo;
}

// decode box for anchor n of image b; matches reference op-by-op (no FMA contraction)
__device__ __forceinline__ float4 decode_box(const float* __restrict__ bbox,
                                             int b, unsigned int n,
                                             float hmax, float wmax) {
  unsigned int a = n % 3u;
  unsigned int pix = n / 3u;
  unsigned int y = pix / (unsigned int)WW;
  unsigned int x = pix % (unsigned int)WW;
  float yc = ((float)y + 0.5f) * 4.0f;   // exact in f32
  float xc = ((float)x + 0.5f) * 4.0f;   // exact in f32
  float hx = (a == 0) ? 16.0f : ((a == 1) ? 22.4f : 11.2f);
  float hy = (a == 0) ? 16.0f : ((a == 1) ? 11.2f : 22.4f);
  float ay1 = __fsub_rn(yc, hy), ax1 = __fsub_rn(xc, hx);
  float ay2 = __fadd_rn(yc, hy), ax2 = __fadd_rn(xc, hx);
  float ah = __fsub_rn(ay2, ay1), aw = __fsub_rn(ax2, ax1);
  float acy = __fadd_rn(ay1, __fmul_rn(0.5f, ah));
  float acx = __fadd_rn(ax1, __fmul_rn(0.5f, aw));
  const float* d = bbox + ((size_t)b * NPER + n) * 4u;
  float dy = d[0], dx = d[1];
  float dh = fminf(fmaxf(d[2], -BBOX_CLIP_F), BBOX_CLIP_F);
  float dw = fminf(fmaxf(d[3], -BBOX_CLIP_F), BBOX_CLIP_F);
  float cy = __fadd_rn(__fmul_rn(dy, ah), acy);
  float cx = __fadd_rn(__fmul_rn(dx, aw), acx);
  float hh = __fmul_rn(expf(dh), ah);
  float wwv = __fmul_rn(expf(dw), aw);
  float y1 = __fsub_rn(cy, __fmul_rn(0.5f, hh));
  float x1 = __fsub_rn(cx, __fmul_rn(0.5f, wwv));
  float y2 = __fadd_rn(cy, __fmul_rn(0.5f, hh));
  float x2 = __fadd_rn(cx, __fmul_rn(0.5f, wwv));
  y1 = fminf(fmaxf(y1, 0.0f), hmax);
  x1 = fminf(fmaxf(x1, 0.0f), wmax);
  y2 = fminf(fmaxf(y2, 0.0f), hmax);
  x2 = fminf(fmaxf(x2, 0.0f), wmax);
  return make_float4(y1, x1, y2, x2);
}

// reference IoU, exact op order
__device__ __forceinline__ float iou_ref(float4 bi, float4 bj) {
  float yA = fmaxf(bi.x, bj.x);
  float xA = fmaxf(bi.y, bj.y);
  float yB = fminf(bi.z, bj.z);
  float xB = fminf(bi.w, bj.w);
  float inter = __fmul_rn(fmaxf(__fsub_rn(yB, yA), 0.0f),
                          fmaxf(__fsub_rn(xB, xA), 0.0f));
  float a1 = __fmul_rn(__fsub_rn(bi.z, bi.x), __fsub_rn(bi.w, bi.y));
  float a2 = __fmul_rn(__fsub_rn(bj.z, bj.x), __fsub_rn(bj.w, bj.y));
  float den = __fadd_rn(__fsub_rn(__fadd_rn(a1, a2), inter), 1e-8f);
  return __fdiv_rn(inter, den);
}

// ---------------- K0: zero ws prefix ----------------
__global__ void k_zero(unsigned int* __restrict__ p, int n) {
  int i = blockIdx.x * blockDim.x + threadIdx.x;
  if (i < n) p[i] = 0u;
}

// ---------------- K1: head GEMM, xor-aligned slot reduction ----------------
__global__ __launch_bounds__(256) void k_head(
    const float* __restrict__ feats, const float* __restrict__ w_cls,
    const float* __restrict__ b_cls, const float* __restrict__ w_reg,
    const float* __restrict__ b_reg, float* __restrict__ out_cls,
    float* __restrict__ out_bbox) {
  const int lane = threadIdx.x & 63;
  const int wid = blockIdx.x * (blockDim.x >> 6) + (threadIdx.x >> 6);
  const int nw = gridDim.x * (blockDim.x >> 6);
  const int k0 = lane << 2;
  const int l15 = lane & 15;
  const int ol = ((l15 & 1) << 3) | ((l15 & 2) << 1) | ((l15 & 4) >> 1) |
                 ((l15 & 8) >> 3);  // brev4 — this lane's final output

  float wreg[4][16];
#pragma unroll
  for (int j = 0; j < 16; ++j) {
    const int o = ol ^ j;
#pragma unroll
    for (int kk = 0; kk < 4; ++kk) {
      wreg[kk][j] = (o < 3) ? w_cls[(k0 + kk) * 3 + o]
                            : (o < 15 ? w_reg[(k0 + kk) * 12 + (o - 3)] : 0.0f);
    }
  }
  const float bias = (ol < 3) ? b_cls[ol] : (ol < 15 ? b_reg[ol - 3] : 0.0f);

  for (int r = wid; r < NROWS; r += nw) {
    const float4 f4 = *(const float4*)(feats + (size_t)r * 256 + k0);
    float a[16];
#pragma unroll
    for (int j = 0; j < 16; ++j) {
      a[j] = f4.x * wreg[0][j];
      a[j] += f4.y * wreg[1][j];
      a[j] += f4.z * wreg[2][j];
      a[j] += f4.w * wreg[3][j];
    }
#pragma unroll
    for (int s = 0; s < 8; ++s) a[s] += __shfl_xor(a[8 + s], 1, 64);
#pragma unroll
    for (int s = 0; s < 4; ++s) a[s] += __shfl_xor(a[4 + s], 2, 64);
#pragma unroll
    for (int s = 0; s < 2; ++s) a[s] += __shfl_xor(a[2 + s], 4, 64);
    a[0] += __shfl_xor(a[1], 8, 64);
    a[0] += __shfl_xor(a[0], 16, 64);
    a[0] += __shfl_xor(a[0], 32, 64);
    if (lane < 16 && ol < 15) {
      float v = a[0] + bias;
      if (ol < 3) out_cls[(size_t)r * 3 + ol] = v;
      else        out_bbox[(size_t)r * 12 + (ol - 3)] = v;
    }
  }
}

// ---------------- K2: 12-bit prefix histogram (LDS-staged) ----------------
__global__ __launch_bounds__(256) void k_hist(const float* __restrict__ out_cls,
                                              unsigned int* __restrict__ hist) {
  const int b = blockIdx.y;
  __shared__ unsigned int h[4096];
  for (int i = threadIdx.x; i < 4096; i += blockDim.x) h[i] = 0u;
  __syncthreads();
  for (int i = blockIdx.x * blockDim.x + threadIdx.x; i < NPER;
       i += gridDim.x * blockDim.x) {
    unsigned int u = score_u(out_cls[(size_t)b * NPER + i]);
    atomicAdd(&h[u >> 20], 1u);
  }
  __syncthreads();
  for (int i = threadIdx.x; i < 4096; i += blockDim.x)
    if (h[i]) atomicAdd(&hist[b * 4096 + i], h[i]);
}

// ---------------- K3: coarse threshold bin scan (1 block / image) ----------------
__global__ __launch_bounds__(1024) void k_thresh(const unsigned int* __restrict__ hist,
                                                 unsigned int* __restrict__ meta_T) {
  const int b = blockIdx.x;
  const int t = threadIdx.x;
  __shared__ unsigned int sums[1024];
  unsigned int hb[4];
  unsigned int s = 0u;
#pragma unroll
  for (int q = 0; q < 4; ++q) {
    int bin = 4095 - (t * 4 + q);   // descending bins
    hb[q] = hist[b * 4096 + bin];
    s += hb[q];
  }
  sums[t] = s;
  __syncthreads();
  for (int off = 1; off < 1024; off <<= 1) {
    unsigned int v = (t >= off) ? sums[t - off] : 0u;
    __syncthreads();
    sums[t] += v;
    __syncthreads();
  }
  unsigned int excl = sums[t] - s;  // count in bins above my chunk
  if (excl < PRE_K && excl + s >= PRE_K) {
    unsigned int c = excl;
#pragma unroll
    for (int q = 0; q < 4; ++q) {
      c += hb[q];
      if (c >= PRE_K) { meta_T[b] = (unsigned int)(4095 - (t * 4 + q)); break; }
    }
  }
}

// ---------------- K3b: refine histogram (next 12 bits, items in bin T only) ----------------
__global__ __launch_bounds__(256) void k_hist2(const float* __restrict__ out_cls,
                                               const unsigned int* __restrict__ meta_T,
                                               unsigned int* __restrict__ hist2) {
  const int b = blockIdx.y;
  const unsigned int T = meta_T[b];
  __shared__ unsigned int h[4096];
  for (int i = threadIdx.x; i < 4096; i += blockDim.x) h[i] = 0u;
  __syncthreads();
  for (int i = blockIdx.x * blockDim.x + threadIdx.x; i < NPER;
       i += gridDim.x * blockDim.x) {
    unsigned int u = score_u(out_cls[(size_t)b * NPER + i]);
    if ((u >> 20) == T) atomicAdd(&h[(u >> 8) & 0xFFFu], 1u);
  }
  __syncthreads();
  for (int i = threadIdx.x; i < 4096; i += blockDim.x)
    if (h[i]) atomicAdd(&hist2[b * 4096 + i], h[i]);
}

// ---------------- K3c: refined 24-bit threshold (1 block / image) ----------------
__global__ __launch_bounds__(1024) void k_thresh2(const unsigned int* __restrict__ hist,
                                                  const unsigned int* __restrict__ hist2,
                                                  const unsigned int* __restrict__ meta_T,
                                                  unsigned int* __restrict__ meta_T24) {
  const int b = blockIdx.x;
  const int t = threadIdx.x;
  const unsigned int T = meta_T[b];
  __shared__ unsigned int sums[1024];
  __shared__ unsigned int c0s;
  unsigned int c0 = 0u;
  for (int i = t; i < 4096; i += 1024)
    if ((unsigned int)i > T) c0 += hist[b * 4096 + i];
  sums[t] = c0;
  __syncthreads();
  for (int off = 512; off > 0; off >>= 1) {
    if (t < off) sums[t] += sums[t + off];
    __syncthreads();
  }
  if (t == 0) c0s = sums[0];
  __syncthreads();
  const unsigned int C0 = c0s;
  __syncthreads();
  unsigned int hb[4];
  unsigned int s = 0u;
#pragma unroll
  for (int q = 0; q < 4; ++q) {
    int bin = 4095 - (t * 4 + q);
    hb[q] = hist2[b * 4096 + bin];
    s += hb[q];
  }
  sums[t] = s;
  __syncthreads();
  for (int off = 1; off < 1024; off <<= 1) {
    unsigned int v = (t >= off) ? sums[t - off] : 0u;
    __syncthreads();
    sums[t] += v;
    __syncthreads();
  }
  unsigned int excl = sums[t] - s;
  if (C0 + excl < PRE_K && C0 + excl + s >= PRE_K) {
    unsigned int c = C0 + excl;
#pragma unroll
    for (int q = 0; q < 4; ++q) {
      c += hb[q];
      if (c >= PRE_K) {
        meta_T24[b] = (T << 12) | (unsigned int)(4095 - (t * 4 + q));
        break;
      }
    }
  }
}

// ---------------- K4: compact candidates (24-bit threshold) ----------------
__global__ __launch_bounds__(256) void k_compact(const float* __restrict__ out_cls,
                                                 const unsigned int* __restrict__ meta_T24,
                                                 unsigned int* __restrict__ cand_count,
                                                 unsigned long long* __restrict__ cand) {
  const int b = blockIdx.y;
  const unsigned int T24 = meta_T24[b];
  for (int i = blockIdx.x * blockDim.x + threadIdx.x; i < NPER;
       i += gridDim.x * blockDim.x) {
    unsigned int u = score_u(out_cls[(size_t)b * NPER + i]);
    if ((u >> 8) >= T24) {
      unsigned int pos = atomicAdd(&cand_count[b], 1u);
      if (pos < CAP)
        cand[(size_t)b * CAP + pos] =
            ((unsigned long long)u << 32) | (unsigned int)(~(unsigned int)i);
    }
  }
}

// ---------------- K5: adaptive bitonic sort (desc) + gather/decode top-2000 ----------------
// 1024 threads: R3->R4 A/B showed the 256-thread version cost ~60us — parallelism
// per pass beats the 16-wave barrier cost. Keep 1024.
__global__ __launch_bounds__(1024) void k_sort(const unsigned long long* __restrict__ cand,
                                               const unsigned int* __restrict__ cand_count,
                                               const float* __restrict__ out_bbox,
                                               const float* __restrict__ img_info,
                                               float* __restrict__ sboxes,
                                               float* __restrict__ sscores) {
  const int b = blockIdx.x;
  const int t = threadIdx.x;
  __shared__ unsigned long long keys[CAP];   // 64 KiB
  unsigned int cc = cand_count[b];
  if (cc > CAP) cc = CAP;
  int n = 2048;
  while ((unsigned int)n < cc) n <<= 1;
  for (int i = t; i < n; i += 1024) keys[i] = cand[(size_t)b * CAP + i];
  __syncthreads();
  for (int k = 2; k <= n; k <<= 1) {
    for (int j = k >> 1; j > 0; j >>= 1) {
      for (int i = t; i < n; i += 1024) {
        int ixj = i ^ j;
        if (ixj > i) {
          unsigned long long a = keys[i], c = keys[ixj];
          bool up = ((i & k) == 0);
          bool sw = up ? (a < c) : (a > c);   // descending overall
          if (sw) { keys[i] = c; keys[ixj] = a; }
        }
      }
      __syncthreads();
    }
  }
  const float hmax = img_info[b * 2 + 0];
  const float wmax = img_info[b * 2 + 1];
  for (int i = t; i < PRE_K; i += 1024) {
    unsigned long long key = keys[i];
    unsigned int u = (unsigned int)(key >> 32);
    unsigned int idx = ~(unsigned int)(key & 0xFFFFFFFFull);
    float sc = __uint_as_float(u & 0x7FFFFFFFu);
    float4 bx = decode_box(out_bbox, b, idx, hmax, wmax);
    ((float4*)sboxes)[(size_t)b * PRE_K + i] = bx;
    sscores[(size_t)b * PRE_K + i] = sc;
  }
}

// ---------------- K6: pairwise suppression mask ----------------
__global__ __launch_bounds__(64) void k_mask(const float* __restrict__ sboxes,
                                             unsigned long long* __restrict__ mask) {
  const int b = blockIdx.z;
  const int rb = blockIdx.x;
  const int cb = blockIdx.y;
  const int t = threadIdx.x;
  __shared__ float4 cbox[64];
  const int col0 = cb * 64;
  {
    int c = col0 + t;
    cbox[t] = (c < PRE_K) ? ((const float4*)sboxes)[(size_t)b * PRE_K + c]
                          : make_float4(0.f, 0.f, 0.f, 0.f);
  }
  __syncthreads();
  const int i = rb * 64 + t;
  if (i >= PRE_K) return;
  float4 bi = ((const float4*)sboxes)[(size_t)b * PRE_K + i];
  unsigned long long bits = 0ull;
#pragma unroll 8
  for (int j = 0; j < 64; ++j) {
    int c = col0 + j;
    if (c > i && c < PRE_K) {
      if (iou_ref(bi, cbox[j]) > 0.7f) bits |= (1ull << j);
    }
  }
  mask[((size_t)b * MROWS + i) * MW + cb] = bits;
}

// ---------------- K7: scalar-pipe keep scan, branch-free alive-set walk ----------------
// Per 64-row group: alive = ~w (w = suppression word from previous groups, SGPR).
// Walk set bits: j = ctz(alive); keep j; alive &= ~(diag_j | bit_j). Rows
// suppressed in-group are cleared from the set and never visited — the serial
// chain touches only kept rows (~POST_K total), each a short scalar chain
// (s_ff1 + 2 v_readlane + s_andn2), no branches in the body.
#define MLOAD(BUF, G)                                                     \
  {                                                                       \
    _Pragma("unroll") for (int _k = 0; _k < 32; ++_k) {                   \
      int _row = (G) * 64 + 2 * _k + psel;                                \
      (BUF)[_k] = (_row < PRE_K) ? M[(size_t)(G) * 2048 + 64 * _k + lane] \
                                 : 0ull;                                  \
    }                                                                     \
  }
#define DLOAD(DST, G)                                                     \
  {                                                                       \
    int _row = (G) * 64 + lane;                                           \
    (DST) = ((G) < 32 && _row < PRE_K) ? M[(size_t)_row * MW + (G)] : 0ull; \
  }
#define GSTEP(G, MCUR, MNEXT, DCUR, DNEXT)                                \
  do {                                                                    \
    MLOAD(MNEXT, (G) + 1);                                                \
    DLOAD(DNEXT, (G) + 1);                                                \
    unsigned long long w = bcast64(remv, (G)) | bcast64(remv, (G) + 32);  \
    unsigned long long alive = ~w;                                        \
    if ((G) == 31) alive &= (1ull << (PRE_K - 31 * 64)) - 1ull;           \
    unsigned long long kept = 0ull;                                       \
    while (alive) {                                                       \
      int j = __builtin_ctzll(alive);                                     \
      unsigned long long bit = 1ull << j;                                 \
      kept |= bit;                                                        \
      unsigned long long dj = bcast64((DCUR), j);                         \
      alive &= ~(dj | bit);                                               \
    }                                                                     \
    int pc = __popcll(kept);                                              \
    if (nk + pc >= POST_K) {                                              \
      int need = POST_K - nk;                                             \
      unsigned long long k2 = kept;                                       \
      for (int _t = 0; _t < need; ++_t) k2 &= k2 - 1;                     \
      kept ^= k2;   /* keep only the first `need` set bits */             \
      if (lane == 0) keepw[b * 32 + (G)] = kept;                          \
      stop = 1;                                                           \
    } else {                                                              \
      nk += pc;                                                           \
      if (lane == 0) keepw[b * 32 + (G)] = kept;                          \
      unsigned long long keptv = kept >> psel;                            \
      _Pragma("unroll") for (int _q = 0; _q < 32; ++_q) {                 \
        unsigned long long sel = 0ull - ((keptv >> (2 * _q)) & 1ull);     \
        remv |= (MCUR)[_q] & sel;                                         \
      }                                                                   \
    }                                                                     \
  } while (0)

__global__ __launch_bounds__(64, 1) void k_scan(
    const unsigned long long* __restrict__ mask,
    unsigned long long* __restrict__ keepw) {
  const int b = blockIdx.x;
  const int lane = threadIdx.x;
  const int psel = lane >> 5;   // row parity this lane covers in pair loads
  const unsigned long long* M = mask + (size_t)b * MROWS * MW;

  unsigned long long mbA[32], mbB[32], dA, dB;
  unsigned long long remv = 0ull;
  int nk = 0, stop = 0;

  MLOAD(mbA, 0);
  DLOAD(dA, 0);
  for (int g = 0; g < 32; g += 2) {
    GSTEP(g, mbA, mbB, dA, dB);
    if (stop) break;
    GSTEP(g + 1, mbB, mbA, dB, dA);
    if (stop) break;
  }
}

// ---------------- K8: rank reconstruction + write rois / roi_scores ----------------
__global__ __launch_bounds__(64) void k_write(const float* __restrict__ sboxes,
                                              const float* __restrict__ sscores,
                                              const unsigned long long* __restrict__ keepw,
                                              float* __restrict__ rois,
                                              float* __restrict__ rsc) {
  const int b = blockIdx.x;
  const int lane = threadIdx.x;
  unsigned long long w = (lane < 32) ? keepw[b * 32 + lane] : 0ull;
  int pc = __popcll(w);
  int pref = pc;
#pragma unroll
  for (int off = 1; off < 64; off <<= 1) {
    int v = __shfl_up(pref, off, 64);
    if (lane >= off) pref += v;
  }
  const int excl = pref - pc;
  const int Ktot = __shfl(pref, 63, 64);
  int rank = excl;
  unsigned long long ww = w;
  while (ww) {
    int j = __builtin_ctzll(ww);
    ww &= ww - 1;
    int row = lane * 64 + j;
    ((float4*)rois)[(size_t)b * POST_K + rank] =
        ((const float4*)sboxes)[(size_t)b * PRE_K + row];
    rsc[(size_t)b * POST_K + rank] = sscores[(size_t)b * PRE_K + row];
    ++rank;
  }
  float4 pad = ((const float4*)sboxes)[(size_t)b * PRE_K + 0];
  for (int i = Ktot + lane; i < POST_K; i += 64) {
    ((float4*)rois)[(size_t)b * POST_K + i] = pad;
    rsc[(size_t)b * POST_K + i] = -1.0f;
  }
}

// ---------------- launch ----------------
extern "C" void kernel_launch(void* const* d_in, const int* in_sizes, int n_in,
                              void* d_out, int out_size, void* d_ws, size_t ws_size,
                              hipStream_t stream) {
  const float* feats    = (const float*)d_in[0];
  const float* img_info = (const float*)d_in[1];
  const float* w_cls    = (const float*)d_in[2];
  const float* b_cls    = (const float*)d_in[3];
  const float* w_reg    = (const float*)d_in[4];
  const float* b_reg    = (const float*)d_in[5];

  float* out = (float*)d_out;
  float* out_cls  = out;              // [2,208,336,3]  = 419328
  float* out_bbox = out + 419328;     // [2,208,336,12] = 1677312
  float* out_rois = out + 2096640;    // [2,1000,4]     = 8000
  float* out_rsc  = out + 2104640;    // [2,1000]       = 2000

  char* ws = (char*)d_ws;
  unsigned int* hist        = (unsigned int*)(ws + WS_HIST);
  unsigned int* hist2       = (unsigned int*)(ws + WS_HIST2);
  unsigned int* meta_T      = (unsigned int*)(ws + WS_META);
  unsigned int* meta_T24    = (unsigned int*)(ws + WS_META24);
  unsigned int* cand_count  = (unsigned int*)(ws + WS_CCNT);
  unsigned long long* keepw = (unsigned long long*)(ws + WS_KEEPW);
  unsigned long long* cand  = (unsigned long long*)(ws + WS_CAND);
  float* sboxes             = (float*)(ws + WS_SBOX);
  float* sscores            = (float*)(ws + WS_SSC);
  unsigned long long* mask  = (unsigned long long*)(ws + WS_MASK);

  k_zero<<<(WS_ZERO_WORDS + 255) / 256, 256, 0, stream>>>((unsigned int*)ws, WS_ZERO_WORDS);
  k_head<<<2048, 256, 0, stream>>>(feats, w_cls, b_cls, w_reg, b_reg, out_cls, out_bbox);
  k_hist<<<dim3(128, NB), 256, 0, stream>>>(out_cls, hist);
  k_thresh<<<NB, 1024, 0, stream>>>(hist, meta_T);
  k_hist2<<<dim3(128, NB), 256, 0, stream>>>(out_cls, meta_T, hist2);
  k_thresh2<<<NB, 1024, 0, stream>>>(hist, hist2, meta_T, meta_T24);
  k_compact<<<dim3(128, NB), 256, 0, stream>>>(out_cls, meta_T24, cand_count, cand);
  k_sort<<<NB, 1024, 0, stream>>>(cand, cand_count, out_bbox, img_info, sboxes, sscores);
  k_mask<<<dim3(32, 32, NB), 64, 0, stream>>>(sboxes, mask);
  k_scan<<<NB, 64, 0, stream>>>(mask, keepw);
  k_write<<<NB, 64, 0, stream>>>(sboxes, sscores, keepw, out_rois, out_rsc);
}